// Round 7
// baseline (903.061 us; speedup 1.0000x reference)
//
#include <hip/hip_runtime.h>
#include <cstdint>

#define GXD 480
#define GYD 360
#define NHD 32
#define NPTS 120000
#define MPAD 120064           // NPTS padded to multiple of 256 (469*256)
#define MB128 (MPAD/128)      // 938 M-tiles of 128 rows
#define SEGR 129600           // 360*360 possible ids
#define NSEG (GXD*GYD)        // 172800
#define EPSB 1e-5f

using short8 = __attribute__((ext_vector_type(8))) short;   // 8 bf16 in 4 VGPRs
using f32x4  = __attribute__((ext_vector_type(4))) float;   // MFMA accumulator

// ---- bf16 helpers ----
__device__ __forceinline__ float bf2f(unsigned short u) {
    return __uint_as_float(((unsigned int)u) << 16);
}
__device__ __forceinline__ unsigned short f2bf(float f) {
    unsigned int u = __float_as_uint(f);
    u += 0x7fffu + ((u >> 16) & 1u);   // round-to-nearest-even
    return (unsigned short)(u >> 16);
}
// bn+relu on a packed bf16 pair; hardware RNE pack (1 instr vs ~9)
__device__ __forceinline__ unsigned int bnrelu_pack(unsigned int wv, float sc0, float sh0,
                                                    float sc1, float sh1)
{
    float lo = __uint_as_float(wv << 16);
    float hi = __uint_as_float(wv & 0xffff0000u);
    lo = fmaxf(fmaf(lo, sc0, sh0), 0.f);
    hi = fmaxf(fmaf(hi, sc1, sh1), 0.f);
    unsigned int r;
    asm("v_cvt_pk_bf16_f32 %0, %1, %2" : "=v"(r) : "v"(lo), "v"(hi));
    return r;
}

// ---- async global->LDS, 16B per lane (dest = wave-uniform base + lane*16) ----
__device__ __forceinline__ void async16(const unsigned short* g, unsigned short* l)
{
    __builtin_amdgcn_global_load_lds(
        (const __attribute__((address_space(1))) unsigned int*)g,
        (__attribute__((address_space(3))) unsigned int*)l, 16, 0, 0);
}

// ---- bn0 stats ----
__global__ __launch_bounds__(256) void bn0_stats_kernel(
    const float* __restrict__ fea, float* __restrict__ s0, float* __restrict__ q0)
{
    float s[7] = {0,0,0,0,0,0,0}, q[7] = {0,0,0,0,0,0,0};
    for (int p = blockIdx.x * 256 + threadIdx.x; p < NPTS; p += gridDim.x * 256) {
        const float* r = fea + (size_t)p * 7;
#pragma unroll
        for (int f = 0; f < 7; ++f) { float v = r[f]; s[f] += v; q[f] += v * v; }
    }
    __shared__ float red[256];
    int t = threadIdx.x;
#pragma unroll
    for (int f = 0; f < 7; ++f) {
        red[t] = s[f]; __syncthreads();
        for (int o = 128; o > 0; o >>= 1) {
            if (t < o) red[t] += red[t + o];
            __syncthreads();
        }
        if (t == 0) atomicAdd(&s0[f], red[0]);
        __syncthreads();
        red[t] = q[f]; __syncthreads();
        for (int o = 128; o > 0; o >>= 1) {
            if (t < o) red[t] += red[t + o];
            __syncthreads();
        }
        if (t == 0) atomicAdd(&q0[f], red[0]);
        __syncthreads();
    }
}

// ---- fold bn0 into W1 ----
__global__ void prep0_kernel(const float* __restrict__ s0, const float* __restrict__ q0,
                             const float* __restrict__ g0, const float* __restrict__ b0,
                             const float* __restrict__ W1, const float* __restrict__ b1,
                             float* __restrict__ W1p, float* __restrict__ b1p)
{
    __shared__ float sc[7], sh[7];
    int t = threadIdx.x;
    if (t < 7) {
        float m = s0[t] / (float)NPTS;
        float v = q0[t] / (float)NPTS - m * m;
        float inv = 1.0f / sqrtf(fmaxf(v, 0.f) + EPSB);
        sc[t] = g0[t] * inv;
        sh[t] = b0[t] - m * g0[t] * inv;
    }
    __syncthreads();
    if (t < 64) {
        float acc = b1[t];
#pragma unroll
        for (int f = 0; f < 7; ++f) {
            W1p[f * 64 + t] = W1[f * 64 + t] * sc[f];
            acc += sh[f] * W1[f * 64 + t];
        }
        b1p[t] = acc;
    }
}

__global__ void prep_bn_kernel(const float* __restrict__ sum, const float* __restrict__ sq,
                               const float* __restrict__ g, const float* __restrict__ b,
                               float* __restrict__ sc, float* __restrict__ sh, int C)
{
    int c = blockIdx.x * blockDim.x + threadIdx.x;
    if (c < C) {
        float m = sum[c] / (float)NPTS;
        float v = sq[c] / (float)NPTS - m * m;
        float inv = 1.0f / sqrtf(fmaxf(v, 0.f) + EPSB);
        sc[c] = g[c] * inv;
        sh[c] = b[c] - m * g[c] * inv;
    }
}

// ---- in-place bn+relu over Y[MPAD][C] (memory-bound, VALU hidden under BW) ----
template<int C>
__global__ __launch_bounds__(256) void bnrelu_kernel(
    unsigned short* __restrict__ Y,
    const float* __restrict__ sc, const float* __restrict__ sh)
{
    __shared__ float scs[C], shs[C];
    int t = threadIdx.x;
    for (int i = t; i < C; i += 256) { scs[i] = sc[i]; shs[i] = sh[i]; }
    __syncthreads();
    const size_t total8 = (size_t)MPAD * C / 8;
    for (size_t i = (size_t)blockIdx.x * 256 + t; i < total8; i += (size_t)gridDim.x * 256) {
        int c0 = (int)((i * 8) & (size_t)(C - 1));
        uint4 v = *(const uint4*)(Y + i * 8);
        float4 s0 = *(const float4*)&scs[c0];
        float4 s1 = *(const float4*)&scs[c0 + 4];
        float4 h0 = *(const float4*)&shs[c0];
        float4 h1 = *(const float4*)&shs[c0 + 4];
        uint4 o;
        o.x = bnrelu_pack(v.x, s0.x, h0.x, s0.y, h0.y);
        o.y = bnrelu_pack(v.y, s0.z, h0.z, s0.w, h0.w);
        o.z = bnrelu_pack(v.z, s1.x, h1.x, s1.y, h1.y);
        o.w = bnrelu_pack(v.w, s1.z, h1.z, s1.w, h1.w);
        *(uint4*)(Y + i * 8) = o;
    }
}

// ---- weight transpose+cast: Wt[n][k] = bf16(W[k][n]) ----
__global__ __launch_bounds__(256) void wtrans_kernel(const float* __restrict__ W,
                                                     unsigned short* __restrict__ Wt,
                                                     int K, int N)
{
    int i = blockIdx.x * 256 + threadIdx.x;
    if (i < K * N) {
        int k = i / N, n = i % N;
        Wt[(size_t)n * K + k] = f2bf(W[i]);
    }
}

// ---- layer 1 v2: y1(bf16) = fea @ W1' + b1' (K=7, Nc=64) + fp32 col stats ----
__global__ __launch_bounds__(256) void layer1_kernel(
    const float* __restrict__ fea, const float* __restrict__ W1p, const float* __restrict__ b1p,
    unsigned short* __restrict__ y1, float* __restrict__ sum1, float* __restrict__ sq1)
{
    __shared__ float Wl[448], bl[64];
    __shared__ float feaL[256 * 7];
    __shared__ float colsum[64], colsq[64];
    int t = threadIdx.x;
    int p0 = blockIdx.x * 256;
    for (int i = t; i < 448; i += 256) Wl[i] = W1p[i];
    if (t < 64) { bl[t] = b1p[t]; colsum[t] = 0.f; colsq[t] = 0.f; }
    int nval7 = (NPTS - p0) * 7;                 // valid feature words in this block
    for (int i = t; i < 256 * 7; i += 256)
        feaL[i] = (i < nval7) ? fea[(size_t)p0 * 7 + i] : 0.f;
    __syncthreads();
    int cg = t & 7, pt = t >> 3;                 // 8 col-groups x 32 point-threads
    float s[8] = {}, q[8] = {};
#pragma unroll
    for (int it = 0; it < 8; ++it) {
        int row = it * 32 + pt;
        bool valid = (p0 + row) < NPTS;
        float f[7];
#pragma unroll
        for (int ff = 0; ff < 7; ++ff) f[ff] = feaL[row * 7 + ff];
        float vj[8];
#pragma unroll
        for (int j = 0; j < 8; ++j) {
            int c = cg * 8 + j;
            float v = bl[c];
#pragma unroll
            for (int ff = 0; ff < 7; ++ff) v = fmaf(f[ff], Wl[ff * 64 + c], v);
            vj[j] = v;
            if (valid) { s[j] += v; q[j] += v * v; }
        }
        uint4 ow;
        ow.x = (unsigned int)f2bf(vj[0]) | ((unsigned int)f2bf(vj[1]) << 16);
        ow.y = (unsigned int)f2bf(vj[2]) | ((unsigned int)f2bf(vj[3]) << 16);
        ow.z = (unsigned int)f2bf(vj[4]) | ((unsigned int)f2bf(vj[5]) << 16);
        ow.w = (unsigned int)f2bf(vj[6]) | ((unsigned int)f2bf(vj[7]) << 16);
        *(uint4*)(y1 + (size_t)(p0 + row) * 64 + cg * 8) = ow;
    }
#pragma unroll
    for (int off = 8; off < 64; off <<= 1) {
#pragma unroll
        for (int j = 0; j < 8; ++j) {
            s[j] += __shfl_xor(s[j], off);
            q[j] += __shfl_xor(q[j], off);
        }
    }
    if ((t & 63) < 8) {                          // one leader per cg per wave
#pragma unroll
        for (int j = 0; j < 8; ++j) {
            atomicAdd(&colsum[cg * 8 + j], s[j]);
            atomicAdd(&colsq[cg * 8 + j], q[j]);
        }
    }
    __syncthreads();
    if (t < 64) {
        atomicAdd(&sum1[t], colsum[t]);
        atomicAdd(&sq1[t], colsq[t]);
    }
}

// ---- MFMA GEMM v13 (R4, best measured): cooperative 128x128 tile, 2-deep ----
// Kept for L2 (K=64 too short for the M-loop structure to pay).
template<int K, int NC, bool STATS>
__global__ __launch_bounds__(256) void gemm_quad(
    const unsigned short* __restrict__ A, const unsigned short* __restrict__ Wt,
    const float* __restrict__ bias, unsigned short* __restrict__ Y,
    float* __restrict__ osum, float* __restrict__ osq)
{
    __shared__ __align__(16) unsigned short lds[16384];   // A[2][128][32], B[2][128][32]
    __shared__ float colsum[128], colsq[128];
    int t = threadIdx.x;
    int w = t >> 6, ln = t & 63, quad = ln >> 4, lr = ln & 15;
    int wr = w >> 1, wc = w & 1;
    const int mbase = blockIdx.y * 128;
    const int cbase = blockIdx.x * 128;
    unsigned short* Asl = lds;
    unsigned short* Bsl = lds + 8192;

    if (STATS && t < 128) { colsum[t] = 0.f; colsq[t] = 0.f; }
    __syncthreads();

    const int srow = w * 16 + (ln >> 2);
    const int koff = (ln & 3) * 8;

    auto stage = [&](int buf, int kt) {
#pragma unroll
        for (int half = 0; half < 2; ++half) {
            int row = half * 64 + srow;
            async16(A  + (size_t)(mbase + row) * K + kt + koff,
                    Asl + buf * 4096 + half * 2048 + w * 512 + ln * 8);
            async16(Wt + (size_t)(cbase + row) * K + kt + koff,
                    Bsl + buf * 4096 + half * 2048 + w * 512 + ln * 8);
        }
    };

    f32x4 acc[4][4];
#pragma unroll
    for (int i = 0; i < 4; ++i)
#pragma unroll
        for (int j = 0; j < 4; ++j) acc[i][j] = (f32x4){0.f, 0.f, 0.f, 0.f};

    stage(0, 0);
    stage(1, 32);

    constexpr int NR = K / 32;
#pragma unroll
    for (int r = 0; r < NR; ++r) {
        const int buf = r & 1;
        if (r + 1 < NR)
            asm volatile("s_waitcnt vmcnt(4)" ::: "memory");
        else
            asm volatile("s_waitcnt vmcnt(0)" ::: "memory");
        asm volatile("s_barrier" ::: "memory");
        short8 af[4], bfr[4];
#pragma unroll
        for (int mi = 0; mi < 4; ++mi)
            af[mi] = *(const short8*)&Asl[buf * 4096 + (wr * 64 + mi * 16 + lr) * 32 + quad * 8];
#pragma unroll
        for (int ni = 0; ni < 4; ++ni)
            bfr[ni] = *(const short8*)&Bsl[buf * 4096 + (wc * 64 + ni * 16 + lr) * 32 + quad * 8];
        asm volatile("s_waitcnt lgkmcnt(0)" ::: "memory");
        asm volatile("s_barrier" ::: "memory");
        if (r + 2 < NR)
            stage(buf, (r + 2) * 32);
#pragma unroll
        for (int mi = 0; mi < 4; ++mi)
#pragma unroll
            for (int ni = 0; ni < 4; ++ni)
                acc[mi][ni] = __builtin_amdgcn_mfma_f32_16x16x32_bf16(
                    af[mi], bfr[ni], acc[mi][ni], 0, 0, 0);
    }
    __syncthreads();

    unsigned short* Cw = lds + w * 4096;
#pragma unroll
    for (int ni = 0; ni < 4; ++ni) {
        int col = ni * 16 + lr;
        float bv = bias[cbase + wc * 64 + col];
        float s = 0.f, q = 0.f;
#pragma unroll
        for (int mi = 0; mi < 4; ++mi) {
            int rb = mi * 16 + quad * 4;
#pragma unroll
            for (int r = 0; r < 4; ++r) {
                float v = acc[mi][ni][r] + bv;
                Cw[(rb + r) * 64 + col] = f2bf(v);
                if (STATS && (mbase + wr * 64 + rb + r) < NPTS) { s += v; q += v * v; }
            }
        }
        if (STATS) {
            atomicAdd(&colsum[wc * 64 + col], s);
            atomicAdd(&colsq[wc * 64 + col], q);
        }
    }
#pragma unroll
    for (int i = 0; i < 8; ++i) {
        int idx = i * 64 + ln;
        int row = idx >> 3, colq = (idx & 7) * 8;
        *(uint4*)(Y + (size_t)(mbase + wr * 64 + row) * NC + cbase + wc * 64 + colq) =
            *(const uint4*)&Cw[row * 64 + colq];
    }
    if (STATS) {
        __syncthreads();
        if (t < 128) {
            atomicAdd(&osum[blockIdx.x * 128 + t], colsum[t]);
            atomicAdd(&osq[blockIdx.x * 128 + t], colsq[t]);
        }
    }
}

// ---- MFMA GEMM v16: M-LOOP with persistent B in LDS ----
// Block owns a 64-col strip: B ([64][K]) loaded ONCE, then ~4 M-tiles of 128
// rows stream through 3 rotating A-slabs (prefetch distance 2, ONE barrier per
// round -- the 3-slab rotation + per-wave lgkmcnt(0)-before-barrier makes the
// WAR barrier unnecessary). Rounds run continuously across tiles; waits are
// vmcnt(2) steady-state, vmcnt(0) only on the final global round. Tile
// epilogue C-stages into the free 3rd slab (wave-private 1KB strips,
// XOR-swizzled), drains loads with vmcnt(4) (in-order retirement => prefix),
// one barrier, resumes.
template<int K, int NC, bool STATS>
__global__ __launch_bounds__(256) void gemm_ml(
    const unsigned short* __restrict__ A, const unsigned short* __restrict__ Wt,
    const float* __restrict__ bias, unsigned short* __restrict__ Y,
    float* __restrict__ osum, float* __restrict__ osq)
{
    constexpr int NR = K / 32;
    __shared__ __align__(16) unsigned short Bsl[NR * 2048];   // [NR][64 cols][32 k]
    __shared__ __align__(16) unsigned short Asl[3 * 4096];    // 3 slabs [128 rows][32 k]
    __shared__ float colsum[64], colsq[64];
    int t = threadIdx.x;
    int w = t >> 6, ln = t & 63, quad = ln >> 4, lr = ln & 15;
    int wr = w >> 1, wc = w & 1;
    const int cbase = blockIdx.x * 64;
    const int by = blockIdx.y, NB = gridDim.y;
    const int nt = 1 + (MB128 - 1 - by) / NB;      // tiles for this block

    if (STATS && t < 64) { colsum[t] = 0.f; colsq[t] = 0.f; }

    const int srow = w * 16 + (ln >> 2);           // 0..63
    const int koff = (ln & 3) * 8;

    // B resident for whole block
#pragma unroll
    for (int r = 0; r < NR; ++r)
        async16(Wt + (size_t)(cbase + srow) * K + r * 32 + koff,
                Bsl + r * 2048 + w * 512 + ln * 8);

    auto stageA = [&](int slab, int mbs, int r) {
#pragma unroll
        for (int half = 0; half < 2; ++half)
            async16(A + (size_t)(mbs + half * 64 + srow) * K + r * 32 + koff,
                    Asl + slab * 4096 + half * 2048 + w * 512 + ln * 8);
    };

    int mb = by * 128;
    stageA(0, mb, 0);
    stageA(1, mb, 1);

    f32x4 acc[4][2];
#pragma unroll
    for (int i = 0; i < 4; ++i) {
        acc[i][0] = (f32x4){0.f, 0.f, 0.f, 0.f};
        acc[i][1] = (f32x4){0.f, 0.f, 0.f, 0.f};
    }

    int slab = 0;                                   // slab of current global round
    for (int i = 0; i < nt; ++i) {
        mb = (by + i * NB) * 128;
        const int mbn = (by + (i + 1) * NB) * 128;  // next tile base (if any)
        const bool lastt = (i == nt - 1);
#pragma unroll
        for (int r = 0; r < NR; ++r) {
            if (r == 0) {
                if (i == 0) {
                    asm volatile("s_waitcnt vmcnt(2)" ::: "memory");
                    asm volatile("s_barrier" ::: "memory");
                }
                // i>0: epilogue's vmcnt(4)+barrier already published this slab
            } else {
                if (lastt && r == NR - 1)
                    asm volatile("s_waitcnt vmcnt(0)" ::: "memory");
                else
                    asm volatile("s_waitcnt vmcnt(2)" ::: "memory");
                asm volatile("s_barrier" ::: "memory");
            }
            int s2 = slab + 2; if (s2 >= 3) s2 -= 3;
            if (r + 2 < NR)                 stageA(s2, mb, r + 2);
            else if (r == NR - 2 && !lastt) stageA(s2, mbn, 0);
            // r == NR-1: deferred past epilogue (slab s2 becomes C-stage area)
            short8 af[4], bfr[2];
#pragma unroll
            for (int mi = 0; mi < 4; ++mi)
                af[mi] = *(const short8*)&Asl[slab * 4096 + wr * 2048 + (mi * 16 + lr) * 32 + quad * 8];
#pragma unroll
            for (int ni = 0; ni < 2; ++ni)
                bfr[ni] = *(const short8*)&Bsl[r * 2048 + (wc * 32 + ni * 16 + lr) * 32 + quad * 8];
            asm volatile("s_waitcnt lgkmcnt(0)" ::: "memory");
#pragma unroll
            for (int mi = 0; mi < 4; ++mi)
#pragma unroll
                for (int ni = 0; ni < 2; ++ni)
                    acc[mi][ni] = __builtin_amdgcn_mfma_f32_16x16x32_bf16(
                        af[mi], bfr[ni], acc[mi][ni], 0, 0, 0);
            ++slab; if (slab == 3) slab = 0;
        }
        // ---- tile epilogue ----
        int cs = slab + 1; if (cs >= 3) cs -= 3;    // (g_last+2)%3: dead slab
        // bias + stats into acc
#pragma unroll
        for (int ni = 0; ni < 2; ++ni) {
            int col = wc * 32 + ni * 16 + lr;
            float bv = bias[cbase + col];
            float s = 0.f, q = 0.f;
#pragma unroll
            for (int mi = 0; mi < 4; ++mi)
#pragma unroll
                for (int rr = 0; rr < 4; ++rr) {
                    float v = acc[mi][ni][rr] + bv;
                    acc[mi][ni][rr] = v;
                    if (STATS && (mb + wr * 64 + mi * 16 + quad * 4 + rr) < NPTS) { s += v; q += v * v; }
                }
            if (STATS) { atomicAdd(&colsum[col], s); atomicAdd(&colsq[col], q); }
        }
        // C-stage per 16-row chunk into this wave's 1KB strip of slab cs.
        // Same-wave DS ordering makes write->read barrier-free (R4 precedent).
        unsigned short* strip = Asl + cs * 4096 + w * 512;
#pragma unroll
        for (int mi = 0; mi < 4; ++mi) {
#pragma unroll
            for (int ni = 0; ni < 2; ++ni)
#pragma unroll
                for (int rr = 0; rr < 4; ++rr) {
                    int row = quad * 4 + rr;
                    int c = (ni * 16 + lr) ^ (quad << 3);   // bank swizzle
                    strip[row * 32 + c] = f2bf(acc[mi][ni][rr]);
                }
            int row = ln >> 2, colq = (ln & 3) * 8;
            int colq2 = colq ^ ((row >> 2) << 3);           // matching un-swizzle
            uint4 vv = *(const uint4*)&strip[row * 32 + colq2];
            *(uint4*)(Y + (size_t)(mb + wr * 64 + mi * 16 + row) * NC + cbase + wc * 32 + colq) = vv;
        }
        // retire next-tile round-0 loads (2 oldest; in-order prefix), publish
        asm volatile("s_waitcnt vmcnt(4)" ::: "memory");
        asm volatile("s_barrier" ::: "memory");
        if (!lastt) stageA(cs, mbn, 1);             // next-tile round 1 into cs
#pragma unroll
        for (int mi = 0; mi < 4; ++mi) {
            acc[mi][0] = (f32x4){0.f, 0.f, 0.f, 0.f};
            acc[mi][1] = (f32x4){0.f, 0.f, 0.f, 0.f};
        }
    }
    if (STATS) {
        __syncthreads();
        if (t < 64) {
            atomicAdd(&osum[cbase + t], colsum[t]);
            atomicAdd(&osq[cbase + t], colsq[t]);
        }
    }
}

// ---- sort machinery: histogram, 3-phase exclusive scan, index scatter ----
__global__ __launch_bounds__(256) void hist_kernel(const int* __restrict__ xy,
                                                   int* __restrict__ cnt)
{
    int p = blockIdx.x * 256 + threadIdx.x;
    if (p < NPTS) {
        int id = xy[(size_t)p * 2] * GYD + xy[(size_t)p * 2 + 1];
        atomicAdd(&cnt[id], 1);
    }
}

__global__ __launch_bounds__(256) void scanA_kernel(const int* __restrict__ cnt,
                                                    int* __restrict__ csum)
{
    __shared__ int red[256];
    int t = threadIdx.x, base = blockIdx.x * 2048;
    int s = 0;
    for (int i = t; i < 2048; i += 256) {
        int idx = base + i;
        if (idx < SEGR) s += cnt[idx];
    }
    red[t] = s; __syncthreads();
    for (int o = 128; o > 0; o >>= 1) { if (t < o) red[t] += red[t + o]; __syncthreads(); }
    if (t == 0) csum[blockIdx.x] = red[0];
}

__global__ void scanB_kernel(int* __restrict__ csum, int* __restrict__ offs)
{
    if (threadIdx.x == 0) {
        int run = 0;
        for (int i = 0; i < 64; ++i) { int v = csum[i]; csum[i] = run; run += v; }
        offs[SEGR] = run;
    }
}

__global__ __launch_bounds__(256) void scanC_kernel(const int* __restrict__ cnt,
                                                    const int* __restrict__ csum,
                                                    int* __restrict__ offs,
                                                    int* __restrict__ cursor)
{
    __shared__ int red[256];
    int t = threadIdx.x, base = blockIdx.x * 2048;
    int v[8]; int s = 0;
#pragma unroll
    for (int i = 0; i < 8; ++i) {
        int idx = base + t * 8 + i;
        v[i] = (idx < SEGR) ? cnt[idx] : 0;
        s += v[i];
    }
    red[t] = s; __syncthreads();
    for (int o = 1; o < 256; o <<= 1) {
        int x = (t >= o) ? red[t - o] : 0;
        __syncthreads();
        red[t] += x;
        __syncthreads();
    }
    int run = red[t] - s + csum[blockIdx.x];
#pragma unroll
    for (int i = 0; i < 8; ++i) {
        int idx = base + t * 8 + i;
        if (idx < SEGR) { offs[idx] = run; cursor[idx] = run; }
        run += v[i];
    }
}

__global__ __launch_bounds__(256) void scatter_idx_kernel(const int* __restrict__ xy,
                                                          int* __restrict__ cursor,
                                                          int* __restrict__ order)
{
    int p = blockIdx.x * 256 + threadIdx.x;
    if (p < NPTS) {
        int id = xy[(size_t)p * 2] * GYD + xy[(size_t)p * 2 + 1];
        int pos = atomicAdd(&cursor[id], 1);
        order[pos] = p;
    }
}

// ---- fused gather-segmax + partial L5: E[cell][32] (+)= max_pts(y4g) @ W5[g-slice] ----
__global__ __launch_bounds__(256) void segmax_l5_kernel(
    const unsigned short* __restrict__ y4g, const unsigned short* __restrict__ Wt5,
    const int* __restrict__ offs, const int* __restrict__ order,
    int g, float* __restrict__ E)
{
    __shared__ __align__(16) unsigned short seg[64 * 136];
    __shared__ __align__(16) unsigned short w5s[32 * 136];
    __shared__ int offs_s[65];
    int t = threadIdx.x;
    int c0 = blockIdx.x * 64;
    if (t < 65) offs_s[t] = offs[c0 + t];
    {   // stage Wt5[n=0..31][k = g*128 .. +128]
        int n = t >> 3, ko = (t & 7) * 16;
        *(uint4*)&w5s[n * 136 + ko]     = *(const uint4*)(Wt5 + (size_t)n * 512 + g * 128 + ko);
        *(uint4*)&w5s[n * 136 + ko + 8] = *(const uint4*)(Wt5 + (size_t)n * 512 + g * 128 + ko + 8);
    }
    __syncthreads();
    int cell = t >> 2, q = t & 3;
    float mx[32];
#pragma unroll
    for (int i = 0; i < 32; ++i) mx[i] = -3.0e38f;
    int jb = offs_s[cell], je = offs_s[cell + 1];
    for (int j = jb; j < je; ++j) {
        int p = order[j];
        const uint4* rp = (const uint4*)(y4g + (size_t)p * 128 + q * 32);
#pragma unroll
        for (int u = 0; u < 4; ++u) {
            uint4 vv = rp[u];
            unsigned int wv[4] = {vv.x, vv.y, vv.z, vv.w};
#pragma unroll
            for (int k2 = 0; k2 < 4; ++k2) {
                int idx = u * 8 + k2 * 2;
                mx[idx]     = fmaxf(mx[idx],     bf2f((unsigned short)(wv[k2] & 0xffffu)));
                mx[idx + 1] = fmaxf(mx[idx + 1], bf2f((unsigned short)(wv[k2] >> 16)));
            }
        }
    }
    bool empty = (jb == je);
#pragma unroll
    for (int i = 0; i < 16; ++i) {
        float lo = empty ? 0.f : mx[2 * i], hi = empty ? 0.f : mx[2 * i + 1];
        unsigned int pk = (unsigned int)f2bf(lo) | ((unsigned int)f2bf(hi) << 16);
        *(unsigned int*)&seg[cell * 136 + q * 32 + 2 * i] = pk;
    }
    __syncthreads();
    int lane = t & 63, w = t >> 6, quad = lane >> 4, lr = lane & 15;
    f32x4 acc[2];
    acc[0] = (f32x4){0.f, 0.f, 0.f, 0.f};
    acc[1] = (f32x4){0.f, 0.f, 0.f, 0.f};
#pragma unroll
    for (int kt = 0; kt < 4; ++kt) {
        short8 af = *(const short8*)&seg[(w * 16 + lr) * 136 + kt * 32 + quad * 8];
#pragma unroll
        for (int ni = 0; ni < 2; ++ni) {
            short8 bfr = *(const short8*)&w5s[(ni * 16 + lr) * 136 + kt * 32 + quad * 8];
            acc[ni] = __builtin_amdgcn_mfma_f32_16x16x32_bf16(af, bfr, acc[ni], 0, 0, 0);
        }
    }
#pragma unroll
    for (int ni = 0; ni < 2; ++ni) {
        int h = ni * 16 + lr;
#pragma unroll
        for (int r = 0; r < 4; ++r) {
            int cr = w * 16 + quad * 4 + r;
            float* ep = E + (size_t)(c0 + cr) * 32 + h;
            float v = acc[ni][r];
            if (g > 0) v += *ep;
            *ep = v;
        }
    }
}

// ---- output: out[h][cell] = occ ? relu(E[cell][h] + b5[h]) : 0 ----
__global__ __launch_bounds__(256) void out_kernel(
    const float* __restrict__ E, const int* __restrict__ cnt,
    const float* __restrict__ b5, float* __restrict__ out)
{
    int t = threadIdx.x;
    int c0 = blockIdx.x * 64;
    int lane = t & 63, hq = t >> 6;
    int cell = c0 + lane;
    if (c0 >= SEGR) {
#pragma unroll
        for (int j = 0; j < 8; ++j)
            out[(size_t)(hq * 8 + j) * NSEG + cell] = 0.f;
        return;
    }
    bool oc = cnt[cell] > 0;
    float4 e0 = *(const float4*)(E + (size_t)cell * 32 + hq * 8);
    float4 e1 = *(const float4*)(E + (size_t)cell * 32 + hq * 8 + 4);
    float r[8] = {e0.x, e0.y, e0.z, e0.w, e1.x, e1.y, e1.z, e1.w};
#pragma unroll
    for (int j = 0; j < 8; ++j) {
        float v = oc ? fmaxf(r[j] + b5[hq * 8 + j], 0.f) : 0.f;
        out[(size_t)(hq * 8 + j) * NSEG + cell] = v;
    }
}

extern "C" void kernel_launch(void* const* d_in, const int* in_sizes, int n_in,
                              void* d_out, int out_size, void* d_ws, size_t ws_size,
                              hipStream_t stream)
{
    const float* pt_fea = (const float*)d_in[0];
    const int*   xy_ind = (const int*)d_in[1];
    const float* bn0_g  = (const float*)d_in[2];
    const float* bn0_b  = (const float*)d_in[3];
    const float* W1     = (const float*)d_in[4];
    const float* b1     = (const float*)d_in[5];
    const float* bn1_g  = (const float*)d_in[6];
    const float* bn1_b  = (const float*)d_in[7];
    const float* W2     = (const float*)d_in[8];
    const float* b2     = (const float*)d_in[9];
    const float* bn2_g  = (const float*)d_in[10];
    const float* bn2_b  = (const float*)d_in[11];
    const float* W3     = (const float*)d_in[12];
    const float* b3     = (const float*)d_in[13];
    const float* bn3_g  = (const float*)d_in[14];
    const float* bn3_b  = (const float*)d_in[15];
    const float* W4     = (const float*)d_in[16];
    const float* b4     = (const float*)d_in[17];
    const float* W5     = (const float*)d_in[18];
    const float* b5     = (const float*)d_in[19];
    float* out = (float*)d_out;

    // ---- workspace layout (~111 MB, unchanged) ----
    const size_t oY2   = 61472768;                 // MPAD*256*2
    const size_t oE    = oY2 + (size_t)MPAD * 128 * 2;
    const size_t oCnt  = oE + (size_t)SEGR * 32 * 4;
    const size_t oOffs = oCnt + 518400;
    const size_t oCur  = oOffs + 518528;
    const size_t oOrd  = oCur + 518400;
    const size_t oCsum = oOrd + 480000;
    const size_t oSt   = oCsum + 512;
    const size_t oWt2  = oSt + 16384;
    const size_t oWt3  = oWt2 + 16384;
    const size_t oWt4  = oWt3 + 65536;
    const size_t oWt5  = oWt4 + 262144;

    unsigned short* y1   = (unsigned short*)d_ws;
    unsigned short* y3   = (unsigned short*)d_ws;
    unsigned short* y2   = (unsigned short*)((char*)d_ws + oY2);
    unsigned short* y4g  = (unsigned short*)((char*)d_ws + oY2);
    float*          E    = (float*)((char*)d_ws + oE);
    int*            cnt  = (int*)((char*)d_ws + oCnt);
    int*            offs = (int*)((char*)d_ws + oOffs);
    int*            cur  = (int*)((char*)d_ws + oCur);
    int*            ord  = (int*)((char*)d_ws + oOrd);
    int*            csum = (int*)((char*)d_ws + oCsum);
    float*          st   = (float*)((char*)d_ws + oSt);
    unsigned short* Wt2  = (unsigned short*)((char*)d_ws + oWt2);
    unsigned short* Wt3  = (unsigned short*)((char*)d_ws + oWt3);
    unsigned short* Wt4  = (unsigned short*)((char*)d_ws + oWt4);
    unsigned short* Wt5  = (unsigned short*)((char*)d_ws + oWt5);

    float* s0 = st + 0;     float* q0 = st + 8;
    float* W1p = st + 16;   float* b1p = st + 464;
    float* sum1 = st + 528; float* sq1 = st + 592; float* sc1 = st + 656; float* sh1 = st + 720;
    float* sum2 = st + 784; float* sq2 = st + 912; float* sc2 = st + 1040; float* sh2 = st + 1168;
    float* sum3 = st + 1296; float* sq3 = st + 1552; float* sc3 = st + 1808; float* sh3 = st + 2064;

    wtrans_kernel<<<(64 * 128 + 255) / 256, 256, 0, stream>>>(W2, Wt2, 64, 128);
    wtrans_kernel<<<(128 * 256 + 255) / 256, 256, 0, stream>>>(W3, Wt3, 128, 256);
    wtrans_kernel<<<(256 * 512 + 255) / 256, 256, 0, stream>>>(W4, Wt4, 256, 512);
    wtrans_kernel<<<(512 * 32 + 255) / 256, 256, 0, stream>>>(W5, Wt5, 512, 32);

    for (int b = 0; b < 2; ++b) {
        const float* fea_b = pt_fea + (size_t)b * NPTS * 7;
        const int*   xy_b  = xy_ind + (size_t)b * NPTS * 2;
        float*       out_b = out + (size_t)b * NHD * NSEG;

        (void)hipMemsetAsync(st, 0, 2320 * sizeof(float), stream);
        (void)hipMemsetAsync(cnt, 0, (size_t)SEGR * 4, stream);

        bn0_stats_kernel<<<128, 256, 0, stream>>>(fea_b, s0, q0);
        prep0_kernel<<<1, 64, 0, stream>>>(s0, q0, bn0_g, bn0_b, W1, b1, W1p, b1p);
        layer1_kernel<<<MPAD / 256, 256, 0, stream>>>(fea_b, W1p, b1p, y1, sum1, sq1);
        prep_bn_kernel<<<1, 64, 0, stream>>>(sum1, sq1, bn1_g, bn1_b, sc1, sh1, 64);
        bnrelu_kernel<64><<<1024, 256, 0, stream>>>(y1, sc1, sh1);
        gemm_quad<64, 128, true><<<dim3(1, MB128), 256, 0, stream>>>(
            y1, Wt2, b2, y2, sum2, sq2);
        prep_bn_kernel<<<1, 128, 0, stream>>>(sum2, sq2, bn2_g, bn2_b, sc2, sh2, 128);
        bnrelu_kernel<128><<<2048, 256, 0, stream>>>(y2, sc2, sh2);
        gemm_ml<128, 256, true><<<dim3(4, 256), 256, 0, stream>>>(
            y2, Wt3, b3, y3, sum3, sq3);
        prep_bn_kernel<<<1, 256, 0, stream>>>(sum3, sq3, bn3_g, bn3_b, sc3, sh3, 256);
        bnrelu_kernel<256><<<2048, 256, 0, stream>>>(y3, sc3, sh3);

        hist_kernel<<<(NPTS + 255) / 256, 256, 0, stream>>>(xy_b, cnt);
        scanA_kernel<<<64, 256, 0, stream>>>(cnt, csum);
        scanB_kernel<<<1, 64, 0, stream>>>(csum, offs);
        scanC_kernel<<<64, 256, 0, stream>>>(cnt, csum, offs, cur);
        scatter_idx_kernel<<<(NPTS + 255) / 256, 256, 0, stream>>>(xy_b, cur, ord);

        for (int g = 0; g < 4; ++g) {
            gemm_ml<256, 128, false><<<dim3(2, 256), 256, 0, stream>>>(
                y3, Wt4 + (size_t)g * 128 * 256, b4 + g * 128, y4g,
                nullptr, nullptr);
            segmax_l5_kernel<<<SEGR / 64, 256, 0, stream>>>(y4g, Wt5, offs, ord, g, E);
        }
        out_kernel<<<NSEG / 64, 256, 0, stream>>>(E, cnt, b5, out_b);
    }
}

// Round 8
// 834.595 us; speedup vs baseline: 1.0820x; 1.0820x over previous
//
#include <hip/hip_runtime.h>
#include <cstdint>

#define GXD 480
#define GYD 360
#define NHD 32
#define NPTS 120000
#define MPAD 120064           // NPTS padded to multiple of 256 (469*256)
#define MB128 (MPAD/128)      // 938 M-tiles of 128 rows
#define SEGR 129600           // 360*360 possible ids
#define NSEG (GXD*GYD)        // 172800
#define EPSB 1e-5f

using short8 = __attribute__((ext_vector_type(8))) short;   // 8 bf16 in 4 VGPRs
using f32x4  = __attribute__((ext_vector_type(4))) float;   // MFMA accumulator

// ---- bf16 helpers ----
__device__ __forceinline__ float bf2f(unsigned short u) {
    return __uint_as_float(((unsigned int)u) << 16);
}
__device__ __forceinline__ unsigned short f2bf(float f) {
    unsigned int u = __float_as_uint(f);
    u += 0x7fffu + ((u >> 16) & 1u);   // round-to-nearest-even
    return (unsigned short)(u >> 16);
}
// bn+relu on a packed bf16 pair; hardware RNE pack (1 instr vs ~9)
__device__ __forceinline__ unsigned int bnrelu_pack(unsigned int wv, float sc0, float sh0,
                                                    float sc1, float sh1)
{
    float lo = __uint_as_float(wv << 16);
    float hi = __uint_as_float(wv & 0xffff0000u);
    lo = fmaxf(fmaf(lo, sc0, sh0), 0.f);
    hi = fmaxf(fmaf(hi, sc1, sh1), 0.f);
    unsigned int r;
    asm("v_cvt_pk_bf16_f32 %0, %1, %2" : "=v"(r) : "v"(lo), "v"(hi));
    return r;
}

// ---- async global->LDS, 16B per lane (dest = wave-uniform base + lane*16) ----
__device__ __forceinline__ void async16(const unsigned short* g, unsigned short* l)
{
    __builtin_amdgcn_global_load_lds(
        (const __attribute__((address_space(1))) unsigned int*)g,
        (__attribute__((address_space(3))) unsigned int*)l, 16, 0, 0);
}

// ---- bn0 stats ----
__global__ __launch_bounds__(256) void bn0_stats_kernel(
    const float* __restrict__ fea, float* __restrict__ s0, float* __restrict__ q0)
{
    float s[7] = {0,0,0,0,0,0,0}, q[7] = {0,0,0,0,0,0,0};
    for (int p = blockIdx.x * 256 + threadIdx.x; p < NPTS; p += gridDim.x * 256) {
        const float* r = fea + (size_t)p * 7;
#pragma unroll
        for (int f = 0; f < 7; ++f) { float v = r[f]; s[f] += v; q[f] += v * v; }
    }
    __shared__ float red[256];
    int t = threadIdx.x;
#pragma unroll
    for (int f = 0; f < 7; ++f) {
        red[t] = s[f]; __syncthreads();
        for (int o = 128; o > 0; o >>= 1) {
            if (t < o) red[t] += red[t + o];
            __syncthreads();
        }
        if (t == 0) atomicAdd(&s0[f], red[0]);
        __syncthreads();
        red[t] = q[f]; __syncthreads();
        for (int o = 128; o > 0; o >>= 1) {
            if (t < o) red[t] += red[t + o];
            __syncthreads();
        }
        if (t == 0) atomicAdd(&q0[f], red[0]);
        __syncthreads();
    }
}

// ---- fold bn0 into W1 ----
__global__ void prep0_kernel(const float* __restrict__ s0, const float* __restrict__ q0,
                             const float* __restrict__ g0, const float* __restrict__ b0,
                             const float* __restrict__ W1, const float* __restrict__ b1,
                             float* __restrict__ W1p, float* __restrict__ b1p)
{
    __shared__ float sc[7], sh[7];
    int t = threadIdx.x;
    if (t < 7) {
        float m = s0[t] / (float)NPTS;
        float v = q0[t] / (float)NPTS - m * m;
        float inv = 1.0f / sqrtf(fmaxf(v, 0.f) + EPSB);
        sc[t] = g0[t] * inv;
        sh[t] = b0[t] - m * g0[t] * inv;
    }
    __syncthreads();
    if (t < 64) {
        float acc = b1[t];
#pragma unroll
        for (int f = 0; f < 7; ++f) {
            W1p[f * 64 + t] = W1[f * 64 + t] * sc[f];
            acc += sh[f] * W1[f * 64 + t];
        }
        b1p[t] = acc;
    }
}

__global__ void prep_bn_kernel(const float* __restrict__ sum, const float* __restrict__ sq,
                               const float* __restrict__ g, const float* __restrict__ b,
                               float* __restrict__ sc, float* __restrict__ sh, int C)
{
    int c = blockIdx.x * blockDim.x + threadIdx.x;
    if (c < C) {
        float m = sum[c] / (float)NPTS;
        float v = sq[c] / (float)NPTS - m * m;
        float inv = 1.0f / sqrtf(fmaxf(v, 0.f) + EPSB);
        sc[c] = g[c] * inv;
        sh[c] = b[c] - m * g[c] * inv;
    }
}

// ---- in-place bn+relu over Y[MPAD][C] (memory-bound, VALU hidden under BW) ----
template<int C>
__global__ __launch_bounds__(256) void bnrelu_kernel(
    unsigned short* __restrict__ Y,
    const float* __restrict__ sc, const float* __restrict__ sh)
{
    __shared__ float scs[C], shs[C];
    int t = threadIdx.x;
    for (int i = t; i < C; i += 256) { scs[i] = sc[i]; shs[i] = sh[i]; }
    __syncthreads();
    const size_t total8 = (size_t)MPAD * C / 8;
    for (size_t i = (size_t)blockIdx.x * 256 + t; i < total8; i += (size_t)gridDim.x * 256) {
        int c0 = (int)((i * 8) & (size_t)(C - 1));
        uint4 v = *(const uint4*)(Y + i * 8);
        float4 s0 = *(const float4*)&scs[c0];
        float4 s1 = *(const float4*)&scs[c0 + 4];
        float4 h0 = *(const float4*)&shs[c0];
        float4 h1 = *(const float4*)&shs[c0 + 4];
        uint4 o;
        o.x = bnrelu_pack(v.x, s0.x, h0.x, s0.y, h0.y);
        o.y = bnrelu_pack(v.y, s0.z, h0.z, s0.w, h0.w);
        o.z = bnrelu_pack(v.z, s1.x, h1.x, s1.y, h1.y);
        o.w = bnrelu_pack(v.w, s1.z, h1.z, s1.w, h1.w);
        *(uint4*)(Y + i * 8) = o;
    }
}

// ---- weight transpose+cast: Wt[n][k] = bf16(W[k][n]) ----
__global__ __launch_bounds__(256) void wtrans_kernel(const float* __restrict__ W,
                                                     unsigned short* __restrict__ Wt,
                                                     int K, int N)
{
    int i = blockIdx.x * 256 + threadIdx.x;
    if (i < K * N) {
        int k = i / N, n = i % N;
        Wt[(size_t)n * K + k] = f2bf(W[i]);
    }
}

// ---- layer 1 v2: y1(bf16) = fea @ W1' + b1' (K=7, Nc=64) + fp32 col stats ----
__global__ __launch_bounds__(256) void layer1_kernel(
    const float* __restrict__ fea, const float* __restrict__ W1p, const float* __restrict__ b1p,
    unsigned short* __restrict__ y1, float* __restrict__ sum1, float* __restrict__ sq1)
{
    __shared__ float Wl[448], bl[64];
    __shared__ float feaL[256 * 7];
    __shared__ float colsum[64], colsq[64];
    int t = threadIdx.x;
    int p0 = blockIdx.x * 256;
    for (int i = t; i < 448; i += 256) Wl[i] = W1p[i];
    if (t < 64) { bl[t] = b1p[t]; colsum[t] = 0.f; colsq[t] = 0.f; }
    int nval7 = (NPTS - p0) * 7;                 // valid feature words in this block
    for (int i = t; i < 256 * 7; i += 256)
        feaL[i] = (i < nval7) ? fea[(size_t)p0 * 7 + i] : 0.f;
    __syncthreads();
    int cg = t & 7, pt = t >> 3;                 // 8 col-groups x 32 point-threads
    float s[8] = {}, q[8] = {};
#pragma unroll
    for (int it = 0; it < 8; ++it) {
        int row = it * 32 + pt;
        bool valid = (p0 + row) < NPTS;
        float f[7];
#pragma unroll
        for (int ff = 0; ff < 7; ++ff) f[ff] = feaL[row * 7 + ff];
        float vj[8];
#pragma unroll
        for (int j = 0; j < 8; ++j) {
            int c = cg * 8 + j;
            float v = bl[c];
#pragma unroll
            for (int ff = 0; ff < 7; ++ff) v = fmaf(f[ff], Wl[ff * 64 + c], v);
            vj[j] = v;
            if (valid) { s[j] += v; q[j] += v * v; }
        }
        uint4 ow;
        ow.x = (unsigned int)f2bf(vj[0]) | ((unsigned int)f2bf(vj[1]) << 16);
        ow.y = (unsigned int)f2bf(vj[2]) | ((unsigned int)f2bf(vj[3]) << 16);
        ow.z = (unsigned int)f2bf(vj[4]) | ((unsigned int)f2bf(vj[5]) << 16);
        ow.w = (unsigned int)f2bf(vj[6]) | ((unsigned int)f2bf(vj[7]) << 16);
        *(uint4*)(y1 + (size_t)(p0 + row) * 64 + cg * 8) = ow;
    }
#pragma unroll
    for (int off = 8; off < 64; off <<= 1) {
#pragma unroll
        for (int j = 0; j < 8; ++j) {
            s[j] += __shfl_xor(s[j], off);
            q[j] += __shfl_xor(q[j], off);
        }
    }
    if ((t & 63) < 8) {                          // one leader per cg per wave
#pragma unroll
        for (int j = 0; j < 8; ++j) {
            atomicAdd(&colsum[cg * 8 + j], s[j]);
            atomicAdd(&colsq[cg * 8 + j], q[j]);
        }
    }
    __syncthreads();
    if (t < 64) {
        atomicAdd(&sum1[t], colsum[t]);
        atomicAdd(&sq1[t], colsq[t]);
    }
}

// ---- MFMA GEMM v13 (R4, best measured): cooperative 128x128 tile, 2-deep ----
template<int K, int NC, bool STATS>
__global__ __launch_bounds__(256) void gemm_quad(
    const unsigned short* __restrict__ A, const unsigned short* __restrict__ Wt,
    const float* __restrict__ bias, unsigned short* __restrict__ Y,
    float* __restrict__ osum, float* __restrict__ osq)
{
    __shared__ __align__(16) unsigned short lds[16384];   // A[2][128][32], B[2][128][32]
    __shared__ float colsum[128], colsq[128];
    int t = threadIdx.x;
    int w = t >> 6, ln = t & 63, quad = ln >> 4, lr = ln & 15;
    int wr = w >> 1, wc = w & 1;
    const int mbase = blockIdx.y * 128;
    const int cbase = blockIdx.x * 128;
    unsigned short* Asl = lds;
    unsigned short* Bsl = lds + 8192;

    if (STATS && t < 128) { colsum[t] = 0.f; colsq[t] = 0.f; }
    __syncthreads();

    const int srow = w * 16 + (ln >> 2);
    const int koff = (ln & 3) * 8;

    auto stage = [&](int buf, int kt) {
#pragma unroll
        for (int half = 0; half < 2; ++half) {
            int row = half * 64 + srow;
            async16(A  + (size_t)(mbase + row) * K + kt + koff,
                    Asl + buf * 4096 + half * 2048 + w * 512 + ln * 8);
            async16(Wt + (size_t)(cbase + row) * K + kt + koff,
                    Bsl + buf * 4096 + half * 2048 + w * 512 + ln * 8);
        }
    };

    f32x4 acc[4][4];
#pragma unroll
    for (int i = 0; i < 4; ++i)
#pragma unroll
        for (int j = 0; j < 4; ++j) acc[i][j] = (f32x4){0.f, 0.f, 0.f, 0.f};

    stage(0, 0);
    stage(1, 32);

    constexpr int NR = K / 32;
#pragma unroll
    for (int r = 0; r < NR; ++r) {
        const int buf = r & 1;
        if (r + 1 < NR)
            asm volatile("s_waitcnt vmcnt(4)" ::: "memory");
        else
            asm volatile("s_waitcnt vmcnt(0)" ::: "memory");
        asm volatile("s_barrier" ::: "memory");
        short8 af[4], bfr[4];
#pragma unroll
        for (int mi = 0; mi < 4; ++mi)
            af[mi] = *(const short8*)&Asl[buf * 4096 + (wr * 64 + mi * 16 + lr) * 32 + quad * 8];
#pragma unroll
        for (int ni = 0; ni < 4; ++ni)
            bfr[ni] = *(const short8*)&Bsl[buf * 4096 + (wc * 64 + ni * 16 + lr) * 32 + quad * 8];
        asm volatile("s_waitcnt lgkmcnt(0)" ::: "memory");
        asm volatile("s_barrier" ::: "memory");
        if (r + 2 < NR)
            stage(buf, (r + 2) * 32);
#pragma unroll
        for (int mi = 0; mi < 4; ++mi)
#pragma unroll
            for (int ni = 0; ni < 4; ++ni)
                acc[mi][ni] = __builtin_amdgcn_mfma_f32_16x16x32_bf16(
                    af[mi], bfr[ni], acc[mi][ni], 0, 0, 0);
    }
    __syncthreads();

    unsigned short* Cw = lds + w * 4096;
#pragma unroll
    for (int ni = 0; ni < 4; ++ni) {
        int col = ni * 16 + lr;
        float bv = bias[cbase + wc * 64 + col];
        float s = 0.f, q = 0.f;
#pragma unroll
        for (int mi = 0; mi < 4; ++mi) {
            int rb = mi * 16 + quad * 4;
#pragma unroll
            for (int r = 0; r < 4; ++r) {
                float v = acc[mi][ni][r] + bv;
                Cw[(rb + r) * 64 + col] = f2bf(v);
                if (STATS && (mbase + wr * 64 + rb + r) < NPTS) { s += v; q += v * v; }
            }
        }
        if (STATS) {
            atomicAdd(&colsum[wc * 64 + col], s);
            atomicAdd(&colsq[wc * 64 + col], q);
        }
    }
#pragma unroll
    for (int i = 0; i < 8; ++i) {
        int idx = i * 64 + ln;
        int row = idx >> 3, colq = (idx & 7) * 8;
        *(uint4*)(Y + (size_t)(mbase + wr * 64 + row) * NC + cbase + wc * 64 + colq) =
            *(const uint4*)&Cw[row * 64 + colq];
    }
    if (STATS) {
        __syncthreads();
        if (t < 128) {
            atomicAdd(&osum[blockIdx.x * 128 + t], colsum[t]);
            atomicAdd(&osq[blockIdx.x * 128 + t], colsq[t]);
        }
    }
}

// ---- sort machinery: histogram, 3-phase exclusive scan, index scatter ----
__global__ __launch_bounds__(256) void hist_kernel(const int* __restrict__ xy,
                                                   int* __restrict__ cnt)
{
    int p = blockIdx.x * 256 + threadIdx.x;
    if (p < NPTS) {
        int id = xy[(size_t)p * 2] * GYD + xy[(size_t)p * 2 + 1];
        atomicAdd(&cnt[id], 1);
    }
}

__global__ __launch_bounds__(256) void scanA_kernel(const int* __restrict__ cnt,
                                                    int* __restrict__ csum)
{
    __shared__ int red[256];
    int t = threadIdx.x, base = blockIdx.x * 2048;
    int s = 0;
    for (int i = t; i < 2048; i += 256) {
        int idx = base + i;
        if (idx < SEGR) s += cnt[idx];
    }
    red[t] = s; __syncthreads();
    for (int o = 128; o > 0; o >>= 1) { if (t < o) red[t] += red[t + o]; __syncthreads(); }
    if (t == 0) csum[blockIdx.x] = red[0];
}

__global__ void scanB_kernel(int* __restrict__ csum, int* __restrict__ offs)
{
    if (threadIdx.x == 0) {
        int run = 0;
        for (int i = 0; i < 64; ++i) { int v = csum[i]; csum[i] = run; run += v; }
        offs[SEGR] = run;
    }
}

__global__ __launch_bounds__(256) void scanC_kernel(const int* __restrict__ cnt,
                                                    const int* __restrict__ csum,
                                                    int* __restrict__ offs,
                                                    int* __restrict__ cursor)
{
    __shared__ int red[256];
    int t = threadIdx.x, base = blockIdx.x * 2048;
    int v[8]; int s = 0;
#pragma unroll
    for (int i = 0; i < 8; ++i) {
        int idx = base + t * 8 + i;
        v[i] = (idx < SEGR) ? cnt[idx] : 0;
        s += v[i];
    }
    red[t] = s; __syncthreads();
    for (int o = 1; o < 256; o <<= 1) {
        int x = (t >= o) ? red[t - o] : 0;
        __syncthreads();
        red[t] += x;
        __syncthreads();
    }
    int run = red[t] - s + csum[blockIdx.x];
#pragma unroll
    for (int i = 0; i < 8; ++i) {
        int idx = base + t * 8 + i;
        if (idx < SEGR) { offs[idx] = run; cursor[idx] = run; }
        run += v[i];
    }
}

__global__ __launch_bounds__(256) void scatter_idx_kernel(const int* __restrict__ xy,
                                                          int* __restrict__ cursor,
                                                          int* __restrict__ order)
{
    int p = blockIdx.x * 256 + threadIdx.x;
    if (p < NPTS) {
        int id = xy[(size_t)p * 2] * GYD + xy[(size_t)p * 2 + 1];
        int pos = atomicAdd(&cursor[id], 1);
        order[pos] = p;
    }
}

// ---- FUSED L4 + segmax + W5 + output: per 64-cell block ----
// Cells [c0,c0+64) own the contiguous sorted-point range [offs[c0], offs[c0+64)).
// For each g-group (128 of 512 L4 cols): gather y3 rows via ord in 64-row
// chunks, MFMA y4 chunk (K=256, dbuf async16, counted vmcnt), stage to LDS,
// per-cell max into registers; then seg @ W5-slice accumulates E in registers
// across g. Final: relu(E+b5), occ mask, coalesced write to out.
// Eliminates the y4g HBM round-trip (246 MB/batch) and the E buffer.
__global__ __launch_bounds__(256) void l4seg_kernel(
    const unsigned short* __restrict__ y3, const unsigned short* __restrict__ Wt4,
    const float* __restrict__ b4, const unsigned short* __restrict__ Wt5,
    const float* __restrict__ b5, const int* __restrict__ offs,
    const int* __restrict__ ord, float* __restrict__ out)
{
    __shared__ __align__(16) unsigned short Asl[2][2048];   // [64 rows][32 k] x2
    __shared__ __align__(16) unsigned short Bsl[2][4096];   // [128 n][32 k] x2
    __shared__ __align__(16) unsigned short y4s[64 * 136];  // y4 chunk / seg
    __shared__ __align__(16) unsigned short w5s[32 * 136];
    __shared__ float b4s[128];
    __shared__ int offs_s[65];
    int t = threadIdx.x;
    int w = t >> 6, ln = t & 63, quad = ln >> 4, lr = ln & 15;
    int c0 = blockIdx.x * 64;
    if (t < 65) offs_s[t] = offs[c0 + t];
    __syncthreads();
    const int jb = offs_s[0], je = offs_s[64];
    if (jb == je) {                               // whole block empty -> zeros
#pragma unroll
        for (int j = 0; j < 8; ++j)
            out[(size_t)(w * 8 + j) * NSEG + c0 + ln] = 0.f;
        return;
    }
    const int cell = t >> 2, q = t & 3;
    const int cjb = offs_s[cell], cje = offs_s[cell + 1];

    f32x4 eacc[2];
    eacc[0] = (f32x4){0.f, 0.f, 0.f, 0.f};
    eacc[1] = (f32x4){0.f, 0.f, 0.f, 0.f};

    const int srow = w * 16 + (ln >> 2);          // staging row 0..63
    const int koff = (ln & 3) * 8;                // staging k-chunk

    for (int g = 0; g < 4; ++g) {
        {   // stage W5 g-slice + b4 g-slice (used only after in-loop barriers)
            int n = t >> 3, ko = (t & 7) * 16;
            *(uint4*)&w5s[n * 136 + ko]     = *(const uint4*)(Wt5 + (size_t)n * 512 + g * 128 + ko);
            *(uint4*)&w5s[n * 136 + ko + 8] = *(const uint4*)(Wt5 + (size_t)n * 512 + g * 128 + ko + 8);
            if (t < 128) b4s[t] = b4[g * 128 + t];
        }
        float mxv[32];
#pragma unroll
        for (int i = 0; i < 32; ++i) mxv[i] = -3.0e38f;

        const unsigned short* Bg = Wt4 + (size_t)(g * 128 + srow) * 256 + koff;

        for (int cs = jb; cs < je; cs += 64) {
            int aj = cs + srow; if (aj >= je) aj = je - 1;   // pad rows: dup last point
            const unsigned short* Ag = y3 + (size_t)ord[aj] * 256 + koff;
            auto stage = [&](int buf, int r) {
                async16(Ag + r * 32,            &Asl[buf][0] + w * 512 + ln * 8);
                async16(Bg + r * 32,            &Bsl[buf][0] + w * 512 + ln * 8);
                async16(Bg + 64 * 256 + r * 32, &Bsl[buf][2048] + w * 512 + ln * 8);
            };
            f32x4 acc[8];
#pragma unroll
            for (int i = 0; i < 8; ++i) acc[i] = (f32x4){0.f, 0.f, 0.f, 0.f};
            stage(0, 0); stage(1, 1);
#pragma unroll
            for (int r = 0; r < 8; ++r) {
                if (r < 7) asm volatile("s_waitcnt vmcnt(3)" ::: "memory");
                else       asm volatile("s_waitcnt vmcnt(0)" ::: "memory");
                asm volatile("s_barrier" ::: "memory");
                const int buf = r & 1;
                short8 af = *(const short8*)&Asl[buf][(w * 16 + lr) * 32 + quad * 8];
                short8 bfr[8];
#pragma unroll
                for (int ni = 0; ni < 8; ++ni)
                    bfr[ni] = *(const short8*)&Bsl[buf][(ni * 16 + lr) * 32 + quad * 8];
                asm volatile("s_waitcnt lgkmcnt(0)" ::: "memory");
                asm volatile("s_barrier" ::: "memory");
                if (r + 2 < 8) stage(buf, r + 2);
#pragma unroll
                for (int ni = 0; ni < 8; ++ni)
                    acc[ni] = __builtin_amdgcn_mfma_f32_16x16x32_bf16(af, bfr[ni], acc[ni], 0, 0, 0);
            }
            // y4 chunk (+b4) -> LDS (wave-private rows)
#pragma unroll
            for (int ni = 0; ni < 8; ++ni) {
                float bv = b4s[ni * 16 + lr];
#pragma unroll
                for (int rr = 0; rr < 4; ++rr)
                    y4s[(w * 16 + quad * 4 + rr) * 136 + ni * 16 + lr] = f2bf(acc[ni][rr] + bv);
            }
            __syncthreads();
            // per-cell running max over this chunk's rows (thread owns cell x 32 cols)
            int lo = cjb > cs ? cjb : cs;
            int hi = cje < cs + 64 ? cje : cs + 64;
            for (int j = lo; j < hi; ++j) {
                const uint4* rp = (const uint4*)&y4s[(j - cs) * 136 + q * 32];
#pragma unroll
                for (int u = 0; u < 4; ++u) {
                    uint4 vv = rp[u];
                    unsigned int wv[4] = {vv.x, vv.y, vv.z, vv.w};
#pragma unroll
                    for (int k2 = 0; k2 < 4; ++k2) {
                        int idx = u * 8 + k2 * 2;
                        mxv[idx]     = fmaxf(mxv[idx],     bf2f((unsigned short)(wv[k2] & 0xffffu)));
                        mxv[idx + 1] = fmaxf(mxv[idx + 1], bf2f((unsigned short)(wv[k2] >> 16)));
                    }
                }
            }
            __syncthreads();                      // before next chunk overwrites y4s
        }
        // pack mx -> seg (reuse y4s); empty cells -> 0 (matches scatter semantics)
        {
            bool empty = (cjb == cje);
#pragma unroll
            for (int i = 0; i < 16; ++i) {
                float lo2 = empty ? 0.f : mxv[2 * i], hi2 = empty ? 0.f : mxv[2 * i + 1];
                unsigned int pk = (unsigned int)f2bf(lo2) | ((unsigned int)f2bf(hi2) << 16);
                *(unsigned int*)&y4s[cell * 136 + q * 32 + 2 * i] = pk;
            }
        }
        __syncthreads();
        // seg @ W5 slice -> accumulate into eacc across g
#pragma unroll
        for (int kt = 0; kt < 4; ++kt) {
            short8 af = *(const short8*)&y4s[(w * 16 + lr) * 136 + kt * 32 + quad * 8];
#pragma unroll
            for (int ni = 0; ni < 2; ++ni) {
                short8 bfr = *(const short8*)&w5s[(ni * 16 + lr) * 136 + kt * 32 + quad * 8];
                eacc[ni] = __builtin_amdgcn_mfma_f32_16x16x32_bf16(af, bfr, eacc[ni], 0, 0, 0);
            }
        }
        __syncthreads();                          // before next g overwrites w5s/y4s/b4s
    }
    // epilogue: relu(eacc+b5), occ mask, LDS stage (pad 33), coalesced write
    float* outs = (float*)&Asl[0][0];             // 64*33*4 = 8448 B, reuses A/B slabs
#pragma unroll
    for (int ni = 0; ni < 2; ++ni) {
        int h = ni * 16 + lr;
        float bv = b5[h];
#pragma unroll
        for (int rr = 0; rr < 4; ++rr) {
            int cr = w * 16 + quad * 4 + rr;
            bool oc = offs_s[cr + 1] > offs_s[cr];
            outs[cr * 33 + h] = oc ? fmaxf(eacc[ni][rr] + bv, 0.f) : 0.f;
        }
    }
    __syncthreads();
#pragma unroll
    for (int j = 0; j < 8; ++j)
        out[(size_t)(w * 8 + j) * NSEG + c0 + ln] = outs[ln * 33 + w * 8 + j];
}

// ---- zero the gx>=360 tail of out (cells SEGR..NSEG never occur) ----
__global__ __launch_bounds__(256) void ztail_kernel(float* __restrict__ out)
{
    int i = blockIdx.x * 256 + threadIdx.x;       // grid exact: 1350*256 = 345600
    const int per = (NSEG - SEGR) / 4;            // 10800 float4 per h
    int h = i / per, c = i % per;
    *(float4*)(out + (size_t)h * NSEG + SEGR + (size_t)c * 4) = make_float4(0.f, 0.f, 0.f, 0.f);
}

extern "C" void kernel_launch(void* const* d_in, const int* in_sizes, int n_in,
                              void* d_out, int out_size, void* d_ws, size_t ws_size,
                              hipStream_t stream)
{
    const float* pt_fea = (const float*)d_in[0];
    const int*   xy_ind = (const int*)d_in[1];
    const float* bn0_g  = (const float*)d_in[2];
    const float* bn0_b  = (const float*)d_in[3];
    const float* W1     = (const float*)d_in[4];
    const float* b1     = (const float*)d_in[5];
    const float* bn1_g  = (const float*)d_in[6];
    const float* bn1_b  = (const float*)d_in[7];
    const float* W2     = (const float*)d_in[8];
    const float* b2     = (const float*)d_in[9];
    const float* bn2_g  = (const float*)d_in[10];
    const float* bn2_b  = (const float*)d_in[11];
    const float* W3     = (const float*)d_in[12];
    const float* b3     = (const float*)d_in[13];
    const float* bn3_g  = (const float*)d_in[14];
    const float* bn3_b  = (const float*)d_in[15];
    const float* W4     = (const float*)d_in[16];
    const float* b4     = (const float*)d_in[17];
    const float* W5     = (const float*)d_in[18];
    const float* b5     = (const float*)d_in[19];
    float* out = (float*)d_out;

    // ---- workspace layout (unchanged offsets; E/y4g regions now unused) ----
    const size_t oY2   = 61472768;                 // MPAD*256*2
    const size_t oE    = oY2 + (size_t)MPAD * 128 * 2;
    const size_t oCnt  = oE + (size_t)SEGR * 32 * 4;
    const size_t oOffs = oCnt + 518400;
    const size_t oCur  = oOffs + 518528;
    const size_t oOrd  = oCur + 518400;
    const size_t oCsum = oOrd + 480000;
    const size_t oSt   = oCsum + 512;
    const size_t oWt2  = oSt + 16384;
    const size_t oWt3  = oWt2 + 16384;
    const size_t oWt4  = oWt3 + 65536;
    const size_t oWt5  = oWt4 + 262144;

    unsigned short* y1   = (unsigned short*)d_ws;
    unsigned short* y3   = (unsigned short*)d_ws;
    unsigned short* y2   = (unsigned short*)((char*)d_ws + oY2);
    int*            cnt  = (int*)((char*)d_ws + oCnt);
    int*            offs = (int*)((char*)d_ws + oOffs);
    int*            cur  = (int*)((char*)d_ws + oCur);
    int*            ord  = (int*)((char*)d_ws + oOrd);
    int*            csum = (int*)((char*)d_ws + oCsum);
    float*          st   = (float*)((char*)d_ws + oSt);
    unsigned short* Wt2  = (unsigned short*)((char*)d_ws + oWt2);
    unsigned short* Wt3  = (unsigned short*)((char*)d_ws + oWt3);
    unsigned short* Wt4  = (unsigned short*)((char*)d_ws + oWt4);
    unsigned short* Wt5  = (unsigned short*)((char*)d_ws + oWt5);

    float* s0 = st + 0;     float* q0 = st + 8;
    float* W1p = st + 16;   float* b1p = st + 464;
    float* sum1 = st + 528; float* sq1 = st + 592; float* sc1 = st + 656; float* sh1 = st + 720;
    float* sum2 = st + 784; float* sq2 = st + 912; float* sc2 = st + 1040; float* sh2 = st + 1168;
    float* sum3 = st + 1296; float* sq3 = st + 1552; float* sc3 = st + 1808; float* sh3 = st + 2064;

    wtrans_kernel<<<(64 * 128 + 255) / 256, 256, 0, stream>>>(W2, Wt2, 64, 128);
    wtrans_kernel<<<(128 * 256 + 255) / 256, 256, 0, stream>>>(W3, Wt3, 128, 256);
    wtrans_kernel<<<(256 * 512 + 255) / 256, 256, 0, stream>>>(W4, Wt4, 256, 512);
    wtrans_kernel<<<(512 * 32 + 255) / 256, 256, 0, stream>>>(W5, Wt5, 512, 32);

    for (int b = 0; b < 2; ++b) {
        const float* fea_b = pt_fea + (size_t)b * NPTS * 7;
        const int*   xy_b  = xy_ind + (size_t)b * NPTS * 2;
        float*       out_b = out + (size_t)b * NHD * NSEG;

        (void)hipMemsetAsync(st, 0, 2320 * sizeof(float), stream);
        (void)hipMemsetAsync(cnt, 0, (size_t)SEGR * 4, stream);

        bn0_stats_kernel<<<128, 256, 0, stream>>>(fea_b, s0, q0);
        prep0_kernel<<<1, 64, 0, stream>>>(s0, q0, bn0_g, bn0_b, W1, b1, W1p, b1p);
        layer1_kernel<<<MPAD / 256, 256, 0, stream>>>(fea_b, W1p, b1p, y1, sum1, sq1);
        prep_bn_kernel<<<1, 64, 0, stream>>>(sum1, sq1, bn1_g, bn1_b, sc1, sh1, 64);
        bnrelu_kernel<64><<<1024, 256, 0, stream>>>(y1, sc1, sh1);
        gemm_quad<64, 128, true><<<dim3(1, MB128), 256, 0, stream>>>(
            y1, Wt2, b2, y2, sum2, sq2);
        prep_bn_kernel<<<1, 128, 0, stream>>>(sum2, sq2, bn2_g, bn2_b, sc2, sh2, 128);
        bnrelu_kernel<128><<<2048, 256, 0, stream>>>(y2, sc2, sh2);
        gemm_quad<128, 256, true><<<dim3(2, MB128), 256, 0, stream>>>(
            y2, Wt3, b3, y3, sum3, sq3);
        prep_bn_kernel<<<1, 256, 0, stream>>>(sum3, sq3, bn3_g, bn3_b, sc3, sh3, 256);
        bnrelu_kernel<256><<<2048, 256, 0, stream>>>(y3, sc3, sh3);

        hist_kernel<<<(NPTS + 255) / 256, 256, 0, stream>>>(xy_b, cnt);
        scanA_kernel<<<64, 256, 0, stream>>>(cnt, csum);
        scanB_kernel<<<1, 64, 0, stream>>>(csum, offs);
        scanC_kernel<<<64, 256, 0, stream>>>(cnt, csum, offs, cur);
        scatter_idx_kernel<<<(NPTS + 255) / 256, 256, 0, stream>>>(xy_b, cur, ord);

        l4seg_kernel<<<SEGR / 64, 256, 0, stream>>>(y3, Wt4, b4, Wt5, b5, offs, ord, out_b);
        ztail_kernel<<<1350, 256, 0, stream>>>(out_b);
    }
}

// Round 9
// 824.261 us; speedup vs baseline: 1.0956x; 1.0125x over previous
//
#include <hip/hip_runtime.h>
#include <cstdint>

#define GXD 480
#define GYD 360
#define NHD 32
#define NPTS 120000
#define MPAD 120064           // NPTS padded to multiple of 256 (469*256)
#define MB128 (MPAD/128)      // 938 M-tiles of 128 rows
#define SEGR 129600           // 360*360 possible ids
#define NSEG (GXD*GYD)        // 172800
#define EPSB 1e-5f

using short8 = __attribute__((ext_vector_type(8))) short;   // 8 bf16 in 4 VGPRs
using f32x4  = __attribute__((ext_vector_type(4))) float;   // MFMA accumulator

// ---- bf16 helpers ----
__device__ __forceinline__ float bf2f(unsigned short u) {
    return __uint_as_float(((unsigned int)u) << 16);
}
__device__ __forceinline__ unsigned short f2bf(float f) {
    unsigned int u = __float_as_uint(f);
    u += 0x7fffu + ((u >> 16) & 1u);   // round-to-nearest-even
    return (unsigned short)(u >> 16);
}
// bn+relu on a packed bf16 pair; hardware RNE pack (1 instr vs ~9)
__device__ __forceinline__ unsigned int bnrelu_pack(unsigned int wv, float sc0, float sh0,
                                                    float sc1, float sh1)
{
    float lo = __uint_as_float(wv << 16);
    float hi = __uint_as_float(wv & 0xffff0000u);
    lo = fmaxf(fmaf(lo, sc0, sh0), 0.f);
    hi = fmaxf(fmaf(hi, sc1, sh1), 0.f);
    unsigned int r;
    asm("v_cvt_pk_bf16_f32 %0, %1, %2" : "=v"(r) : "v"(lo), "v"(hi));
    return r;
}

// ---- async global->LDS, 16B per lane (dest = wave-uniform base + lane*16) ----
__device__ __forceinline__ void async16(const unsigned short* g, unsigned short* l)
{
    __builtin_amdgcn_global_load_lds(
        (const __attribute__((address_space(1))) unsigned int*)g,
        (__attribute__((address_space(3))) unsigned int*)l, 16, 0, 0);
}

// ---- bn0 stats ----
__global__ __launch_bounds__(256) void bn0_stats_kernel(
    const float* __restrict__ fea, float* __restrict__ s0, float* __restrict__ q0)
{
    float s[7] = {0,0,0,0,0,0,0}, q[7] = {0,0,0,0,0,0,0};
    for (int p = blockIdx.x * 256 + threadIdx.x; p < NPTS; p += gridDim.x * 256) {
        const float* r = fea + (size_t)p * 7;
#pragma unroll
        for (int f = 0; f < 7; ++f) { float v = r[f]; s[f] += v; q[f] += v * v; }
    }
    __shared__ float red[256];
    int t = threadIdx.x;
#pragma unroll
    for (int f = 0; f < 7; ++f) {
        red[t] = s[f]; __syncthreads();
        for (int o = 128; o > 0; o >>= 1) {
            if (t < o) red[t] += red[t + o];
            __syncthreads();
        }
        if (t == 0) atomicAdd(&s0[f], red[0]);
        __syncthreads();
        red[t] = q[f]; __syncthreads();
        for (int o = 128; o > 0; o >>= 1) {
            if (t < o) red[t] += red[t + o];
            __syncthreads();
        }
        if (t == 0) atomicAdd(&q0[f], red[0]);
        __syncthreads();
    }
}

// ---- fold bn0 into W1 ----
__global__ void prep0_kernel(const float* __restrict__ s0, const float* __restrict__ q0,
                             const float* __restrict__ g0, const float* __restrict__ b0,
                             const float* __restrict__ W1, const float* __restrict__ b1,
                             float* __restrict__ W1p, float* __restrict__ b1p)
{
    __shared__ float sc[7], sh[7];
    int t = threadIdx.x;
    if (t < 7) {
        float m = s0[t] / (float)NPTS;
        float v = q0[t] / (float)NPTS - m * m;
        float inv = 1.0f / sqrtf(fmaxf(v, 0.f) + EPSB);
        sc[t] = g0[t] * inv;
        sh[t] = b0[t] - m * g0[t] * inv;
    }
    __syncthreads();
    if (t < 64) {
        float acc = b1[t];
#pragma unroll
        for (int f = 0; f < 7; ++f) {
            W1p[f * 64 + t] = W1[f * 64 + t] * sc[f];
            acc += sh[f] * W1[f * 64 + t];
        }
        b1p[t] = acc;
    }
}

__global__ void prep_bn_kernel(const float* __restrict__ sum, const float* __restrict__ sq,
                               const float* __restrict__ g, const float* __restrict__ b,
                               float* __restrict__ sc, float* __restrict__ sh, int C)
{
    int c = blockIdx.x * blockDim.x + threadIdx.x;
    if (c < C) {
        float m = sum[c] / (float)NPTS;
        float v = sq[c] / (float)NPTS - m * m;
        float inv = 1.0f / sqrtf(fmaxf(v, 0.f) + EPSB);
        sc[c] = g[c] * inv;
        sh[c] = b[c] - m * g[c] * inv;
    }
}

// ---- in-place bn+relu over Y[MPAD][C] (memory-bound, VALU hidden under BW) ----
template<int C>
__global__ __launch_bounds__(256) void bnrelu_kernel(
    unsigned short* __restrict__ Y,
    const float* __restrict__ sc, const float* __restrict__ sh)
{
    __shared__ float scs[C], shs[C];
    int t = threadIdx.x;
    for (int i = t; i < C; i += 256) { scs[i] = sc[i]; shs[i] = sh[i]; }
    __syncthreads();
    const size_t total8 = (size_t)MPAD * C / 8;
    for (size_t i = (size_t)blockIdx.x * 256 + t; i < total8; i += (size_t)gridDim.x * 256) {
        int c0 = (int)((i * 8) & (size_t)(C - 1));
        uint4 v = *(const uint4*)(Y + i * 8);
        float4 s0 = *(const float4*)&scs[c0];
        float4 s1 = *(const float4*)&scs[c0 + 4];
        float4 h0 = *(const float4*)&shs[c0];
        float4 h1 = *(const float4*)&shs[c0 + 4];
        uint4 o;
        o.x = bnrelu_pack(v.x, s0.x, h0.x, s0.y, h0.y);
        o.y = bnrelu_pack(v.y, s0.z, h0.z, s0.w, h0.w);
        o.z = bnrelu_pack(v.z, s1.x, h1.x, s1.y, h1.y);
        o.w = bnrelu_pack(v.w, s1.z, h1.z, s1.w, h1.w);
        *(uint4*)(Y + i * 8) = o;
    }
}

// ---- weight transpose+cast: Wt[n][k] = bf16(W[k][n]) ----
__global__ __launch_bounds__(256) void wtrans_kernel(const float* __restrict__ W,
                                                     unsigned short* __restrict__ Wt,
                                                     int K, int N)
{
    int i = blockIdx.x * 256 + threadIdx.x;
    if (i < K * N) {
        int k = i / N, n = i % N;
        Wt[(size_t)n * K + k] = f2bf(W[i]);
    }
}

// ---- layer 1 v2: y1(bf16) = fea @ W1' + b1' (K=7, Nc=64) + fp32 col stats ----
__global__ __launch_bounds__(256) void layer1_kernel(
    const float* __restrict__ fea, const float* __restrict__ W1p, const float* __restrict__ b1p,
    unsigned short* __restrict__ y1, float* __restrict__ sum1, float* __restrict__ sq1)
{
    __shared__ float Wl[448], bl[64];
    __shared__ float feaL[256 * 7];
    __shared__ float colsum[64], colsq[64];
    int t = threadIdx.x;
    int p0 = blockIdx.x * 256;
    for (int i = t; i < 448; i += 256) Wl[i] = W1p[i];
    if (t < 64) { bl[t] = b1p[t]; colsum[t] = 0.f; colsq[t] = 0.f; }
    int nval7 = (NPTS - p0) * 7;                 // valid feature words in this block
    for (int i = t; i < 256 * 7; i += 256)
        feaL[i] = (i < nval7) ? fea[(size_t)p0 * 7 + i] : 0.f;
    __syncthreads();
    int cg = t & 7, pt = t >> 3;                 // 8 col-groups x 32 point-threads
    float s[8] = {}, q[8] = {};
#pragma unroll
    for (int it = 0; it < 8; ++it) {
        int row = it * 32 + pt;
        bool valid = (p0 + row) < NPTS;
        float f[7];
#pragma unroll
        for (int ff = 0; ff < 7; ++ff) f[ff] = feaL[row * 7 + ff];
        float vj[8];
#pragma unroll
        for (int j = 0; j < 8; ++j) {
            int c = cg * 8 + j;
            float v = bl[c];
#pragma unroll
            for (int ff = 0; ff < 7; ++ff) v = fmaf(f[ff], Wl[ff * 64 + c], v);
            vj[j] = v;
            if (valid) { s[j] += v; q[j] += v * v; }
        }
        uint4 ow;
        ow.x = (unsigned int)f2bf(vj[0]) | ((unsigned int)f2bf(vj[1]) << 16);
        ow.y = (unsigned int)f2bf(vj[2]) | ((unsigned int)f2bf(vj[3]) << 16);
        ow.z = (unsigned int)f2bf(vj[4]) | ((unsigned int)f2bf(vj[5]) << 16);
        ow.w = (unsigned int)f2bf(vj[6]) | ((unsigned int)f2bf(vj[7]) << 16);
        *(uint4*)(y1 + (size_t)(p0 + row) * 64 + cg * 8) = ow;
    }
#pragma unroll
    for (int off = 8; off < 64; off <<= 1) {
#pragma unroll
        for (int j = 0; j < 8; ++j) {
            s[j] += __shfl_xor(s[j], off);
            q[j] += __shfl_xor(q[j], off);
        }
    }
    if ((t & 63) < 8) {                          // one leader per cg per wave
#pragma unroll
        for (int j = 0; j < 8; ++j) {
            atomicAdd(&colsum[cg * 8 + j], s[j]);
            atomicAdd(&colsq[cg * 8 + j], q[j]);
        }
    }
    __syncthreads();
    if (t < 64) {
        atomicAdd(&sum1[t], colsum[t]);
        atomicAdd(&sq1[t], colsq[t]);
    }
}

// ---- MFMA GEMM v17: SINGLE-SHOT K-resident 128x128 tile ----
// Entire A+B tile staged up-front (back-to-back async16, max MLP), ONE
// vmcnt(0)+barrier, then an uninterrupted MFMA loop (no per-round waits --
// the per-round wait+barrier convoy was ~3750cy/round across R1/R5/R6).
// Cross-block overlap (2-4 blocks/CU) hides load under compute.
// LDS layout [row][K] with involution swizzle chunk_phys = chunk_log ^ (row&7)
// applied on BOTH the global source and the ds_read (rule #21): kills the
// 8-16-way quad bank conflict of row-aligned layouts.
template<int K, int NC, bool STATS>
__global__ __launch_bounds__(256) void gemm_single(
    const unsigned short* __restrict__ A, const unsigned short* __restrict__ Wt,
    const float* __restrict__ bias, unsigned short* __restrict__ Y,
    float* __restrict__ osum, float* __restrict__ osq)
{
    constexpr int CH  = K / 8;        // 16B chunks per row
    constexpr int RPI = 512 / K;      // rows covered per async16 instr
    constexpr int AI  = 32 / RPI;     // instrs per wave for its 32 rows
    constexpr int NR  = K / 32;
    __shared__ __align__(16) unsigned short lds[2 * 128 * K];  // A then B
    __shared__ float colsum[128], colsq[128];
    int t = threadIdx.x;
    int w = t >> 6, ln = t & 63, quad = ln >> 4, lr = ln & 15;
    int wr = w >> 1, wc = w & 1;
    const int mbase = blockIdx.y * 128;
    const int cbase = blockIdx.x * 128;
    unsigned short* Asl = lds;
    unsigned short* Bsl = lds + 128 * K;

    if (STATS && t < 128) { colsum[t] = 0.f; colsq[t] = 0.f; }

    const int rin = ln / CH;          // row within instr group
    const int cph = ln % CH;          // phys chunk this lane fills
    // stage whole tile: wave w covers rows w*32..w*32+32 of A and of B
#pragma unroll
    for (int i = 0; i < AI; ++i) {
        int row = w * 32 + i * RPI + rin;
        int cl  = cph ^ (row & 7);
        async16(A + (size_t)(mbase + row) * K + cl * 8,
                Asl + (w * 32 + i * RPI) * K + ln * 8);
    }
#pragma unroll
    for (int i = 0; i < AI; ++i) {
        int row = w * 32 + i * RPI + rin;
        int cl  = cph ^ (row & 7);
        async16(Wt + (size_t)(cbase + row) * K + cl * 8,
                Bsl + (w * 32 + i * RPI) * K + ln * 8);
    }

    f32x4 acc[4][4];
#pragma unroll
    for (int i = 0; i < 4; ++i)
#pragma unroll
        for (int j = 0; j < 4; ++j) acc[i][j] = (f32x4){0.f, 0.f, 0.f, 0.f};

    asm volatile("s_waitcnt vmcnt(0)" ::: "memory");   // whole tile in LDS
    asm volatile("s_barrier" ::: "memory");            // published

#pragma unroll
    for (int r = 0; r < NR; ++r) {
        short8 af[4], bfr[4];
        const int cp = (r * 4 + quad) ^ (lr & 7);      // swizzled chunk
#pragma unroll
        for (int mi = 0; mi < 4; ++mi)
            af[mi] = *(const short8*)&Asl[(wr * 64 + mi * 16 + lr) * K + cp * 8];
#pragma unroll
        for (int ni = 0; ni < 4; ++ni)
            bfr[ni] = *(const short8*)&Bsl[(wc * 64 + ni * 16 + lr) * K + cp * 8];
#pragma unroll
        for (int mi = 0; mi < 4; ++mi)
#pragma unroll
            for (int ni = 0; ni < 4; ++ni)
                acc[mi][ni] = __builtin_amdgcn_mfma_f32_16x16x32_bf16(
                    af[mi], bfr[ni], acc[mi][ni], 0, 0, 0);
    }
    __syncthreads();                               // all reads done, reuse LDS for C

    unsigned short* Cw = lds + w * 4096;           // 8KB bf16 strip per wave
    // C/D layout: col=lane&15, row=quad*4+reg
#pragma unroll
    for (int ni = 0; ni < 4; ++ni) {
        int col = ni * 16 + lr;
        float bv = bias[cbase + wc * 64 + col];
        float s = 0.f, q = 0.f;
#pragma unroll
        for (int mi = 0; mi < 4; ++mi) {
            int rb = mi * 16 + quad * 4;
#pragma unroll
            for (int r = 0; r < 4; ++r) {
                float v = acc[mi][ni][r] + bv;
                Cw[(rb + r) * 64 + col] = f2bf(v);
                if (STATS && (mbase + wr * 64 + rb + r) < NPTS) { s += v; q += v * v; }
            }
        }
        if (STATS) {
            atomicAdd(&colsum[wc * 64 + col], s);
            atomicAdd(&colsq[wc * 64 + col], q);
        }
    }
#pragma unroll
    for (int i = 0; i < 8; ++i) {                  // 64x64 tile, full-line uint4 stores
        int idx = i * 64 + ln;
        int row = idx >> 3, colq = (idx & 7) * 8;
        *(uint4*)(Y + (size_t)(mbase + wr * 64 + row) * NC + cbase + wc * 64 + colq) =
            *(const uint4*)&Cw[row * 64 + colq];
    }
    if (STATS) {
        __syncthreads();
        if (t < 128) {
            atomicAdd(&osum[blockIdx.x * 128 + t], colsum[t]);
            atomicAdd(&osq[blockIdx.x * 128 + t], colsq[t]);
        }
    }
}

// ---- sort machinery: histogram, 3-phase exclusive scan, index scatter ----
__global__ __launch_bounds__(256) void hist_kernel(const int* __restrict__ xy,
                                                   int* __restrict__ cnt)
{
    int p = blockIdx.x * 256 + threadIdx.x;
    if (p < NPTS) {
        int id = xy[(size_t)p * 2] * GYD + xy[(size_t)p * 2 + 1];
        atomicAdd(&cnt[id], 1);
    }
}

__global__ __launch_bounds__(256) void scanA_kernel(const int* __restrict__ cnt,
                                                    int* __restrict__ csum)
{
    __shared__ int red[256];
    int t = threadIdx.x, base = blockIdx.x * 2048;
    int s = 0;
    for (int i = t; i < 2048; i += 256) {
        int idx = base + i;
        if (idx < SEGR) s += cnt[idx];
    }
    red[t] = s; __syncthreads();
    for (int o = 128; o > 0; o >>= 1) { if (t < o) red[t] += red[t + o]; __syncthreads(); }
    if (t == 0) csum[blockIdx.x] = red[0];
}

__global__ void scanB_kernel(int* __restrict__ csum, int* __restrict__ offs)
{
    if (threadIdx.x == 0) {
        int run = 0;
        for (int i = 0; i < 64; ++i) { int v = csum[i]; csum[i] = run; run += v; }
        offs[SEGR] = run;
    }
}

__global__ __launch_bounds__(256) void scanC_kernel(const int* __restrict__ cnt,
                                                    const int* __restrict__ csum,
                                                    int* __restrict__ offs,
                                                    int* __restrict__ cursor)
{
    __shared__ int red[256];
    int t = threadIdx.x, base = blockIdx.x * 2048;
    int v[8]; int s = 0;
#pragma unroll
    for (int i = 0; i < 8; ++i) {
        int idx = base + t * 8 + i;
        v[i] = (idx < SEGR) ? cnt[idx] : 0;
        s += v[i];
    }
    red[t] = s; __syncthreads();
    for (int o = 1; o < 256; o <<= 1) {
        int x = (t >= o) ? red[t - o] : 0;
        __syncthreads();
        red[t] += x;
        __syncthreads();
    }
    int run = red[t] - s + csum[blockIdx.x];
#pragma unroll
    for (int i = 0; i < 8; ++i) {
        int idx = base + t * 8 + i;
        if (idx < SEGR) { offs[idx] = run; cursor[idx] = run; }
        run += v[i];
    }
}

__global__ __launch_bounds__(256) void scatter_idx_kernel(const int* __restrict__ xy,
                                                          int* __restrict__ cursor,
                                                          int* __restrict__ order)
{
    int p = blockIdx.x * 256 + threadIdx.x;
    if (p < NPTS) {
        int id = xy[(size_t)p * 2] * GYD + xy[(size_t)p * 2 + 1];
        int pos = atomicAdd(&cursor[id], 1);
        order[pos] = p;
    }
}

// ---- FUSED L4 + segmax + W5 + output v2: single-shot k-half phases ----
// Per (g, chunk, k-half): stage A-half (64 gathered rows x 128k, 16KB, via
// LDS-cached ord) + B-half (128n x 128k, 32KB) back-to-back, ONE vmcnt(0)+
// barrier, 32 MFMA, barrier. 8 waits/chunk (was 32 round-waits x2 barriers).
// Same [row][128] XOR-swizzled layout as gemm_single.
__global__ __launch_bounds__(256) void l4seg_kernel(
    const unsigned short* __restrict__ y3, const unsigned short* __restrict__ Wt4,
    const float* __restrict__ b4, const unsigned short* __restrict__ Wt5,
    const float* __restrict__ b5, const int* __restrict__ offs,
    const int* __restrict__ ord, float* __restrict__ out)
{
    __shared__ __align__(16) unsigned short Asl[64 * 128];    // 16 KB
    __shared__ __align__(16) unsigned short Bsl[128 * 128];   // 32 KB
    __shared__ __align__(16) unsigned short y4s[64 * 136];    // 17.4 KB
    __shared__ __align__(16) unsigned short w5s[32 * 136];    // 8.7 KB
    __shared__ float b4s[128];
    __shared__ int offs_s[65];
    __shared__ int osl[64];
    int t = threadIdx.x;
    int w = t >> 6, ln = t & 63, quad = ln >> 4, lr = ln & 15;
    int c0 = blockIdx.x * 64;
    if (t < 65) offs_s[t] = offs[c0 + t];
    __syncthreads();
    const int jb = offs_s[0], je = offs_s[64];
    if (jb == je) {                               // whole block empty -> zeros
#pragma unroll
        for (int j = 0; j < 8; ++j)
            out[(size_t)(w * 8 + j) * NSEG + c0 + ln] = 0.f;
        return;
    }
    const int cell = t >> 2, q = t & 3;
    const int cjb = offs_s[cell], cje = offs_s[cell + 1];

    f32x4 eacc[2];
    eacc[0] = (f32x4){0.f, 0.f, 0.f, 0.f};
    eacc[1] = (f32x4){0.f, 0.f, 0.f, 0.f};

    const int rin = ln >> 4;                      // row within instr (CH=16)
    const int cph = ln & 15;                      // phys chunk

    for (int g = 0; g < 4; ++g) {
        {   // stage W5 g-slice + b4 g-slice (plain loads; used after barriers)
            int n = t >> 3, ko = (t & 7) * 16;
            *(uint4*)&w5s[n * 136 + ko]     = *(const uint4*)(Wt5 + (size_t)n * 512 + g * 128 + ko);
            *(uint4*)&w5s[n * 136 + ko + 8] = *(const uint4*)(Wt5 + (size_t)n * 512 + g * 128 + ko + 8);
            if (t < 128) b4s[t] = b4[g * 128 + t];
        }
        float mxv[32];
#pragma unroll
        for (int i = 0; i < 32; ++i) mxv[i] = -3.0e38f;

        for (int cs = jb; cs < je; cs += 64) {
            if (t < 64) { int aj = cs + t; osl[t] = ord[aj < je ? aj : je - 1]; }
            __syncthreads();                      // osl visible; prev max done
            f32x4 acc[8];
#pragma unroll
            for (int i = 0; i < 8; ++i) acc[i] = (f32x4){0.f, 0.f, 0.f, 0.f};
#pragma unroll
            for (int h = 0; h < 2; ++h) {
                // stage A-half: wave w covers A rows w*16..w*16+16
#pragma unroll
                for (int i = 0; i < 4; ++i) {
                    int row = w * 16 + i * 4 + rin;
                    int cl  = cph ^ (row & 7);
                    async16(y3 + (size_t)osl[row] * 256 + h * 128 + cl * 8,
                            Asl + (w * 16 + i * 4) * 128 + ln * 8);
                }
                // stage B-half: wave w covers B rows w*32..w*32+32
#pragma unroll
                for (int i = 0; i < 8; ++i) {
                    int row = w * 32 + i * 4 + rin;
                    int cl  = cph ^ (row & 7);
                    async16(Wt4 + (size_t)(g * 128 + row) * 256 + h * 128 + cl * 8,
                            Bsl + (w * 32 + i * 4) * 128 + ln * 8);
                }
                asm volatile("s_waitcnt vmcnt(0)" ::: "memory");
                asm volatile("s_barrier" ::: "memory");
#pragma unroll
                for (int r = 0; r < 4; ++r) {
                    const int cp = (r * 4 + quad) ^ (lr & 7);
                    short8 af = *(const short8*)&Asl[(w * 16 + lr) * 128 + cp * 8];
                    short8 bfr[8];
#pragma unroll
                    for (int ni = 0; ni < 8; ++ni)
                        bfr[ni] = *(const short8*)&Bsl[(ni * 16 + lr) * 128 + cp * 8];
#pragma unroll
                    for (int ni = 0; ni < 8; ++ni)
                        acc[ni] = __builtin_amdgcn_mfma_f32_16x16x32_bf16(af, bfr[ni], acc[ni], 0, 0, 0);
                }
                asm volatile("s_waitcnt lgkmcnt(0)" ::: "memory");  // frag reads done
                asm volatile("s_barrier" ::: "memory");             // safe to restage
            }
            // y4 chunk (+b4) -> LDS (wave-private rows)
#pragma unroll
            for (int ni = 0; ni < 8; ++ni) {
                float bv = b4s[ni * 16 + lr];
#pragma unroll
                for (int rr = 0; rr < 4; ++rr)
                    y4s[(w * 16 + quad * 4 + rr) * 136 + ni * 16 + lr] = f2bf(acc[ni][rr] + bv);
            }
            __syncthreads();
            // per-cell running max (thread owns cell x 32 cols)
            int lo = cjb > cs ? cjb : cs;
            int hi = cje < cs + 64 ? cje : cs + 64;
            for (int j = lo; j < hi; ++j) {
                const uint4* rp = (const uint4*)&y4s[(j - cs) * 136 + q * 32];
#pragma unroll
                for (int u = 0; u < 4; ++u) {
                    uint4 vv = rp[u];
                    unsigned int wv[4] = {vv.x, vv.y, vv.z, vv.w};
#pragma unroll
                    for (int k2 = 0; k2 < 4; ++k2) {
                        int idx = u * 8 + k2 * 2;
                        mxv[idx]     = fmaxf(mxv[idx],     bf2f((unsigned short)(wv[k2] & 0xffffu)));
                        mxv[idx + 1] = fmaxf(mxv[idx + 1], bf2f((unsigned short)(wv[k2] >> 16)));
                    }
                }
            }
            __syncthreads();                      // before next chunk overwrites y4s
        }
        // pack mx -> seg (reuse y4s); empty cells -> 0 (scatter semantics)
        {
            bool empty = (cjb == cje);
#pragma unroll
            for (int i = 0; i < 16; ++i) {
                float lo2 = empty ? 0.f : mxv[2 * i], hi2 = empty ? 0.f : mxv[2 * i + 1];
                unsigned int pk = (unsigned int)f2bf(lo2) | ((unsigned int)f2bf(hi2) << 16);
                *(unsigned int*)&y4s[cell * 136 + q * 32 + 2 * i] = pk;
            }
        }
        __syncthreads();
        // seg @ W5 slice -> accumulate into eacc across g
#pragma unroll
        for (int kt = 0; kt < 4; ++kt) {
            short8 af = *(const short8*)&y4s[(w * 16 + lr) * 136 + kt * 32 + quad * 8];
#pragma unroll
            for (int ni = 0; ni < 2; ++ni) {
                short8 bfr = *(const short8*)&w5s[(ni * 16 + lr) * 136 + kt * 32 + quad * 8];
                eacc[ni] = __builtin_amdgcn_mfma_f32_16x16x32_bf16(af, bfr, eacc[ni], 0, 0, 0);
            }
        }
        __syncthreads();                          // before next g overwrites w5s/y4s/b4s
    }
    // epilogue: relu(eacc+b5), occ mask, LDS stage (pad 33), coalesced write
    float* outs = (float*)&Asl[0];                // 64*33*4 = 8448 B fits in Asl
#pragma unroll
    for (int ni = 0; ni < 2; ++ni) {
        int h = ni * 16 + lr;
        float bv = b5[h];
#pragma unroll
        for (int rr = 0; rr < 4; ++rr) {
            int cr = w * 16 + quad * 4 + rr;
            bool oc = offs_s[cr + 1] > offs_s[cr];
            outs[cr * 33 + h] = oc ? fmaxf(eacc[ni][rr] + bv, 0.f) : 0.f;
        }
    }
    __syncthreads();
#pragma unroll
    for (int j = 0; j < 8; ++j)
        out[(size_t)(w * 8 + j) * NSEG + c0 + ln] = outs[ln * 33 + w * 8 + j];
}

// ---- zero the gx>=360 tail of out (cells SEGR..NSEG never occur) ----
__global__ __launch_bounds__(256) void ztail_kernel(float* __restrict__ out)
{
    int i = blockIdx.x * 256 + threadIdx.x;       // grid exact: 1350*256 = 345600
    const int per = (NSEG - SEGR) / 4;            // 10800 float4 per h
    int h = i / per, c = i % per;
    *(float4*)(out + (size_t)h * NSEG + SEGR + (size_t)c * 4) = make_float4(0.f, 0.f, 0.f, 0.f);
}

extern "C" void kernel_launch(void* const* d_in, const int* in_sizes, int n_in,
                              void* d_out, int out_size, void* d_ws, size_t ws_size,
                              hipStream_t stream)
{
    const float* pt_fea = (const float*)d_in[0];
    const int*   xy_ind = (const int*)d_in[1];
    const float* bn0_g  = (const float*)d_in[2];
    const float* bn0_b  = (const float*)d_in[3];
    const float* W1     = (const float*)d_in[4];
    const float* b1     = (const float*)d_in[5];
    const float* bn1_g  = (const float*)d_in[6];
    const float* bn1_b  = (const float*)d_in[7];
    const float* W2     = (const float*)d_in[8];
    const float* b2     = (const float*)d_in[9];
    const float* bn2_g  = (const float*)d_in[10];
    const float* bn2_b  = (const float*)d_in[11];
    const float* W3     = (const float*)d_in[12];
    const float* b3     = (const float*)d_in[13];
    const float* bn3_g  = (const float*)d_in[14];
    const float* bn3_b  = (const float*)d_in[15];
    const float* W4     = (const float*)d_in[16];
    const float* b4     = (const float*)d_in[17];
    const float* W5     = (const float*)d_in[18];
    const float* b5     = (const float*)d_in[19];
    float* out = (float*)d_out;

    // ---- workspace layout (unchanged offsets; E/y4g regions now unused) ----
    const size_t oY2   = 61472768;                 // MPAD*256*2
    const size_t oE    = oY2 + (size_t)MPAD * 128 * 2;
    const size_t oCnt  = oE + (size_t)SEGR * 32 * 4;
    const size_t oOffs = oCnt + 518400;
    const size_t oCur  = oOffs + 518528;
    const size_t oOrd  = oCur + 518400;
    const size_t oCsum = oOrd + 480000;
    const size_t oSt   = oCsum + 512;
    const size_t oWt2  = oSt + 16384;
    const size_t oWt3  = oWt2 + 16384;
    const size_t oWt4  = oWt3 + 65536;
    const size_t oWt5  = oWt4 + 262144;

    unsigned short* y1   = (unsigned short*)d_ws;
    unsigned short* y3   = (unsigned short*)d_ws;
    unsigned short* y2   = (unsigned short*)((char*)d_ws + oY2);
    int*            cnt  = (int*)((char*)d_ws + oCnt);
    int*            offs = (int*)((char*)d_ws + oOffs);
    int*            cur  = (int*)((char*)d_ws + oCur);
    int*            ord  = (int*)((char*)d_ws + oOrd);
    int*            csum = (int*)((char*)d_ws + oCsum);
    float*          st   = (float*)((char*)d_ws + oSt);
    unsigned short* Wt2  = (unsigned short*)((char*)d_ws + oWt2);
    unsigned short* Wt3  = (unsigned short*)((char*)d_ws + oWt3);
    unsigned short* Wt4  = (unsigned short*)((char*)d_ws + oWt4);
    unsigned short* Wt5  = (unsigned short*)((char*)d_ws + oWt5);

    float* s0 = st + 0;     float* q0 = st + 8;
    float* W1p = st + 16;   float* b1p = st + 464;
    float* sum1 = st + 528; float* sq1 = st + 592; float* sc1 = st + 656; float* sh1 = st + 720;
    float* sum2 = st + 784; float* sq2 = st + 912; float* sc2 = st + 1040; float* sh2 = st + 1168;
    float* sum3 = st + 1296; float* sq3 = st + 1552; float* sc3 = st + 1808; float* sh3 = st + 2064;

    wtrans_kernel<<<(64 * 128 + 255) / 256, 256, 0, stream>>>(W2, Wt2, 64, 128);
    wtrans_kernel<<<(128 * 256 + 255) / 256, 256, 0, stream>>>(W3, Wt3, 128, 256);
    wtrans_kernel<<<(256 * 512 + 255) / 256, 256, 0, stream>>>(W4, Wt4, 256, 512);
    wtrans_kernel<<<(512 * 32 + 255) / 256, 256, 0, stream>>>(W5, Wt5, 512, 32);

    for (int b = 0; b < 2; ++b) {
        const float* fea_b = pt_fea + (size_t)b * NPTS * 7;
        const int*   xy_b  = xy_ind + (size_t)b * NPTS * 2;
        float*       out_b = out + (size_t)b * NHD * NSEG;

        (void)hipMemsetAsync(st, 0, 2320 * sizeof(float), stream);
        (void)hipMemsetAsync(cnt, 0, (size_t)SEGR * 4, stream);

        bn0_stats_kernel<<<128, 256, 0, stream>>>(fea_b, s0, q0);
        prep0_kernel<<<1, 64, 0, stream>>>(s0, q0, bn0_g, bn0_b, W1, b1, W1p, b1p);
        layer1_kernel<<<MPAD / 256, 256, 0, stream>>>(fea_b, W1p, b1p, y1, sum1, sq1);
        prep_bn_kernel<<<1, 64, 0, stream>>>(sum1, sq1, bn1_g, bn1_b, sc1, sh1, 64);
        bnrelu_kernel<64><<<1024, 256, 0, stream>>>(y1, sc1, sh1);
        gemm_single<64, 128, true><<<dim3(1, MB128), 256, 0, stream>>>(
            y1, Wt2, b2, y2, sum2, sq2);
        prep_bn_kernel<<<1, 128, 0, stream>>>(sum2, sq2, bn2_g, bn2_b, sc2, sh2, 128);
        bnrelu_kernel<128><<<2048, 256, 0, stream>>>(y2, sc2, sh2);
        gemm_single<128, 256, true><<<dim3(2, MB128), 256, 0, stream>>>(
            y2, Wt3, b3, y3, sum3, sq3);
        prep_bn_kernel<<<1, 256, 0, stream>>>(sum3, sq3, bn3_g, bn3_b, sc3, sh3, 256);
        bnrelu_kernel<256><<<2048, 256, 0, stream>>>(y3, sc3, sh3);

        hist_kernel<<<(NPTS + 255) / 256, 256, 0, stream>>>(xy_b, cnt);
        scanA_kernel<<<64, 256, 0, stream>>>(cnt, csum);
        scanB_kernel<<<1, 64, 0, stream>>>(csum, offs);
        scanC_kernel<<<64, 256, 0, stream>>>(cnt, csum, offs, cur);
        scatter_idx_kernel<<<(NPTS + 255) / 256, 256, 0, stream>>>(xy_b, cur, ord);

        l4seg_kernel<<<SEGR / 64, 256, 0, stream>>>(y3, Wt4, b4, Wt5, b5, offs, ord, out_b);
        ztail_kernel<<<1350, 256, 0, stream>>>(out_b);
    }
}

// Round 10
// 783.050 us; speedup vs baseline: 1.1533x; 1.0526x over previous
//
#include <hip/hip_runtime.h>
#include <cstdint>

#define GXD 480
#define GYD 360
#define NHD 32
#define NPTS 120000
#define MPAD 120064           // NPTS padded to multiple of 256 (469*256)
#define MB128 (MPAD/128)      // 938 M-tiles of 128 rows
#define SEGR 129600           // 360*360 possible ids
#define NSEG (GXD*GYD)        // 172800
#define EPSB 1e-5f

using short8 = __attribute__((ext_vector_type(8))) short;   // 8 bf16 in 4 VGPRs
using f32x4  = __attribute__((ext_vector_type(4))) float;   // MFMA accumulator

// ---- bf16 helpers ----
__device__ __forceinline__ float bf2f(unsigned short u) {
    return __uint_as_float(((unsigned int)u) << 16);
}
__device__ __forceinline__ unsigned short f2bf(float f) {
    unsigned int u = __float_as_uint(f);
    u += 0x7fffu + ((u >> 16) & 1u);   // round-to-nearest-even
    return (unsigned short)(u >> 16);
}
// bn+relu on a packed bf16 pair; hardware RNE pack (1 instr vs ~9)
__device__ __forceinline__ unsigned int bnrelu_pack(unsigned int wv, float sc0, float sh0,
                                                    float sc1, float sh1)
{
    float lo = __uint_as_float(wv << 16);
    float hi = __uint_as_float(wv & 0xffff0000u);
    lo = fmaxf(fmaf(lo, sc0, sh0), 0.f);
    hi = fmaxf(fmaf(hi, sc1, sh1), 0.f);
    unsigned int r;
    asm("v_cvt_pk_bf16_f32 %0, %1, %2" : "=v"(r) : "v"(lo), "v"(hi));
    return r;
}
__device__ __forceinline__ unsigned int pk_bf16(float lo, float hi)
{
    unsigned int r;
    asm("v_cvt_pk_bf16_f32 %0, %1, %2" : "=v"(r) : "v"(lo), "v"(hi));
    return r;
}

// ---- async global->LDS, 16B per lane (dest = wave-uniform base + lane*16) ----
__device__ __forceinline__ void async16(const unsigned short* g, unsigned short* l)
{
    __builtin_amdgcn_global_load_lds(
        (const __attribute__((address_space(1))) unsigned int*)g,
        (__attribute__((address_space(3))) unsigned int*)l, 16, 0, 0);
}

// ---- bn0 stats ----
__global__ __launch_bounds__(256) void bn0_stats_kernel(
    const float* __restrict__ fea, float* __restrict__ s0, float* __restrict__ q0)
{
    float s[7] = {0,0,0,0,0,0,0}, q[7] = {0,0,0,0,0,0,0};
    for (int p = blockIdx.x * 256 + threadIdx.x; p < NPTS; p += gridDim.x * 256) {
        const float* r = fea + (size_t)p * 7;
#pragma unroll
        for (int f = 0; f < 7; ++f) { float v = r[f]; s[f] += v; q[f] += v * v; }
    }
    __shared__ float red[256];
    int t = threadIdx.x;
#pragma unroll
    for (int f = 0; f < 7; ++f) {
        red[t] = s[f]; __syncthreads();
        for (int o = 128; o > 0; o >>= 1) {
            if (t < o) red[t] += red[t + o];
            __syncthreads();
        }
        if (t == 0) atomicAdd(&s0[f], red[0]);
        __syncthreads();
        red[t] = q[f]; __syncthreads();
        for (int o = 128; o > 0; o >>= 1) {
            if (t < o) red[t] += red[t + o];
            __syncthreads();
        }
        if (t == 0) atomicAdd(&q0[f], red[0]);
        __syncthreads();
    }
}

// ---- fold bn0 into W1 ----
__global__ void prep0_kernel(const float* __restrict__ s0, const float* __restrict__ q0,
                             const float* __restrict__ g0, const float* __restrict__ b0,
                             const float* __restrict__ W1, const float* __restrict__ b1,
                             float* __restrict__ W1p, float* __restrict__ b1p)
{
    __shared__ float sc[7], sh[7];
    int t = threadIdx.x;
    if (t < 7) {
        float m = s0[t] / (float)NPTS;
        float v = q0[t] / (float)NPTS - m * m;
        float inv = 1.0f / sqrtf(fmaxf(v, 0.f) + EPSB);
        sc[t] = g0[t] * inv;
        sh[t] = b0[t] - m * g0[t] * inv;
    }
    __syncthreads();
    if (t < 64) {
        float acc = b1[t];
#pragma unroll
        for (int f = 0; f < 7; ++f) {
            W1p[f * 64 + t] = W1[f * 64 + t] * sc[f];
            acc += sh[f] * W1[f * 64 + t];
        }
        b1p[t] = acc;
    }
}

__global__ void prep_bn_kernel(const float* __restrict__ sum, const float* __restrict__ sq,
                               const float* __restrict__ g, const float* __restrict__ b,
                               float* __restrict__ sc, float* __restrict__ sh, int C)
{
    int c = blockIdx.x * blockDim.x + threadIdx.x;
    if (c < C) {
        float m = sum[c] / (float)NPTS;
        float v = sq[c] / (float)NPTS - m * m;
        float inv = 1.0f / sqrtf(fmaxf(v, 0.f) + EPSB);
        sc[c] = g[c] * inv;
        sh[c] = b[c] - m * g[c] * inv;
    }
}

// ---- in-place bn+relu over Y[MPAD][C] (memory-bound, VALU hidden under BW) ----
template<int C>
__global__ __launch_bounds__(256) void bnrelu_kernel(
    unsigned short* __restrict__ Y,
    const float* __restrict__ sc, const float* __restrict__ sh)
{
    __shared__ float scs[C], shs[C];
    int t = threadIdx.x;
    for (int i = t; i < C; i += 256) { scs[i] = sc[i]; shs[i] = sh[i]; }
    __syncthreads();
    const size_t total8 = (size_t)MPAD * C / 8;
    for (size_t i = (size_t)blockIdx.x * 256 + t; i < total8; i += (size_t)gridDim.x * 256) {
        int c0 = (int)((i * 8) & (size_t)(C - 1));
        uint4 v = *(const uint4*)(Y + i * 8);
        float4 s0 = *(const float4*)&scs[c0];
        float4 s1 = *(const float4*)&scs[c0 + 4];
        float4 h0 = *(const float4*)&shs[c0];
        float4 h1 = *(const float4*)&shs[c0 + 4];
        uint4 o;
        o.x = bnrelu_pack(v.x, s0.x, h0.x, s0.y, h0.y);
        o.y = bnrelu_pack(v.y, s0.z, h0.z, s0.w, h0.w);
        o.z = bnrelu_pack(v.z, s1.x, h1.x, s1.y, h1.y);
        o.w = bnrelu_pack(v.w, s1.z, h1.z, s1.w, h1.w);
        *(uint4*)(Y + i * 8) = o;
    }
}

// ---- weight transpose+cast: Wt[n][k] = bf16(W[k][n]) ----
__global__ __launch_bounds__(256) void wtrans_kernel(const float* __restrict__ W,
                                                     unsigned short* __restrict__ Wt,
                                                     int K, int N)
{
    int i = blockIdx.x * 256 + threadIdx.x;
    if (i < K * N) {
        int k = i / N, n = i % N;
        Wt[(size_t)n * K + k] = f2bf(W[i]);
    }
}

// ---- layer 1 v2: y1(bf16) = fea @ W1' + b1' (K=7, Nc=64) + fp32 col stats ----
__global__ __launch_bounds__(256) void layer1_kernel(
    const float* __restrict__ fea, const float* __restrict__ W1p, const float* __restrict__ b1p,
    unsigned short* __restrict__ y1, float* __restrict__ sum1, float* __restrict__ sq1)
{
    __shared__ float Wl[448], bl[64];
    __shared__ float feaL[256 * 7];
    __shared__ float colsum[64], colsq[64];
    int t = threadIdx.x;
    int p0 = blockIdx.x * 256;
    for (int i = t; i < 448; i += 256) Wl[i] = W1p[i];
    if (t < 64) { bl[t] = b1p[t]; colsum[t] = 0.f; colsq[t] = 0.f; }
    int nval7 = (NPTS - p0) * 7;                 // valid feature words in this block
    for (int i = t; i < 256 * 7; i += 256)
        feaL[i] = (i < nval7) ? fea[(size_t)p0 * 7 + i] : 0.f;
    __syncthreads();
    int cg = t & 7, pt = t >> 3;                 // 8 col-groups x 32 point-threads
    float s[8] = {}, q[8] = {};
#pragma unroll
    for (int it = 0; it < 8; ++it) {
        int row = it * 32 + pt;
        bool valid = (p0 + row) < NPTS;
        float f[7];
#pragma unroll
        for (int ff = 0; ff < 7; ++ff) f[ff] = feaL[row * 7 + ff];
        float vj[8];
#pragma unroll
        for (int j = 0; j < 8; ++j) {
            int c = cg * 8 + j;
            float v = bl[c];
#pragma unroll
            for (int ff = 0; ff < 7; ++ff) v = fmaf(f[ff], Wl[ff * 64 + c], v);
            vj[j] = v;
            if (valid) { s[j] += v; q[j] += v * v; }
        }
        uint4 ow;
        ow.x = (unsigned int)f2bf(vj[0]) | ((unsigned int)f2bf(vj[1]) << 16);
        ow.y = (unsigned int)f2bf(vj[2]) | ((unsigned int)f2bf(vj[3]) << 16);
        ow.z = (unsigned int)f2bf(vj[4]) | ((unsigned int)f2bf(vj[5]) << 16);
        ow.w = (unsigned int)f2bf(vj[6]) | ((unsigned int)f2bf(vj[7]) << 16);
        *(uint4*)(y1 + (size_t)(p0 + row) * 64 + cg * 8) = ow;
    }
#pragma unroll
    for (int off = 8; off < 64; off <<= 1) {
#pragma unroll
        for (int j = 0; j < 8; ++j) {
            s[j] += __shfl_xor(s[j], off);
            q[j] += __shfl_xor(q[j], off);
        }
    }
    if ((t & 63) < 8) {                          // one leader per cg per wave
#pragma unroll
        for (int j = 0; j < 8; ++j) {
            atomicAdd(&colsum[cg * 8 + j], s[j]);
            atomicAdd(&colsq[cg * 8 + j], q[j]);
        }
    }
    __syncthreads();
    if (t < 64) {
        atomicAdd(&sum1[t], colsum[t]);
        atomicAdd(&sq1[t], colsq[t]);
    }
}

// ---- MFMA GEMM v13 (R4, best measured): cooperative 128x128 tile, 2-deep ----
template<int K, int NC, bool STATS>
__global__ __launch_bounds__(256) void gemm_quad(
    const unsigned short* __restrict__ A, const unsigned short* __restrict__ Wt,
    const float* __restrict__ bias, unsigned short* __restrict__ Y,
    float* __restrict__ osum, float* __restrict__ osq)
{
    __shared__ __align__(16) unsigned short lds[16384];   // A[2][128][32], B[2][128][32]
    __shared__ float colsum[128], colsq[128];
    int t = threadIdx.x;
    int w = t >> 6, ln = t & 63, quad = ln >> 4, lr = ln & 15;
    int wr = w >> 1, wc = w & 1;
    const int mbase = blockIdx.y * 128;
    const int cbase = blockIdx.x * 128;
    unsigned short* Asl = lds;
    unsigned short* Bsl = lds + 8192;

    if (STATS && t < 128) { colsum[t] = 0.f; colsq[t] = 0.f; }
    __syncthreads();

    const int srow = w * 16 + (ln >> 2);
    const int koff = (ln & 3) * 8;

    auto stage = [&](int buf, int kt) {
#pragma unroll
        for (int half = 0; half < 2; ++half) {
            int row = half * 64 + srow;
            async16(A  + (size_t)(mbase + row) * K + kt + koff,
                    Asl + buf * 4096 + half * 2048 + w * 512 + ln * 8);
            async16(Wt + (size_t)(cbase + row) * K + kt + koff,
                    Bsl + buf * 4096 + half * 2048 + w * 512 + ln * 8);
        }
    };

    f32x4 acc[4][4];
#pragma unroll
    for (int i = 0; i < 4; ++i)
#pragma unroll
        for (int j = 0; j < 4; ++j) acc[i][j] = (f32x4){0.f, 0.f, 0.f, 0.f};

    stage(0, 0);
    stage(1, 32);

    constexpr int NR = K / 32;
#pragma unroll
    for (int r = 0; r < NR; ++r) {
        const int buf = r & 1;
        if (r + 1 < NR)
            asm volatile("s_waitcnt vmcnt(4)" ::: "memory");
        else
            asm volatile("s_waitcnt vmcnt(0)" ::: "memory");
        asm volatile("s_barrier" ::: "memory");
        short8 af[4], bfr[4];
#pragma unroll
        for (int mi = 0; mi < 4; ++mi)
            af[mi] = *(const short8*)&Asl[buf * 4096 + (wr * 64 + mi * 16 + lr) * 32 + quad * 8];
#pragma unroll
        for (int ni = 0; ni < 4; ++ni)
            bfr[ni] = *(const short8*)&Bsl[buf * 4096 + (wc * 64 + ni * 16 + lr) * 32 + quad * 8];
        asm volatile("s_waitcnt lgkmcnt(0)" ::: "memory");
        asm volatile("s_barrier" ::: "memory");
        if (r + 2 < NR)
            stage(buf, (r + 2) * 32);
#pragma unroll
        for (int mi = 0; mi < 4; ++mi)
#pragma unroll
            for (int ni = 0; ni < 4; ++ni)
                acc[mi][ni] = __builtin_amdgcn_mfma_f32_16x16x32_bf16(
                    af[mi], bfr[ni], acc[mi][ni], 0, 0, 0);
    }
    __syncthreads();

    unsigned short* Cw = lds + w * 4096;
#pragma unroll
    for (int ni = 0; ni < 4; ++ni) {
        int col = ni * 16 + lr;
        float bv = bias[cbase + wc * 64 + col];
        float s = 0.f, q = 0.f;
#pragma unroll
        for (int mi = 0; mi < 4; ++mi) {
            int rb = mi * 16 + quad * 4;
#pragma unroll
            for (int r = 0; r < 4; ++r) {
                float v = acc[mi][ni][r] + bv;
                Cw[(rb + r) * 64 + col] = f2bf(v);
                if (STATS && (mbase + wr * 64 + rb + r) < NPTS) { s += v; q += v * v; }
            }
        }
        if (STATS) {
            atomicAdd(&colsum[wc * 64 + col], s);
            atomicAdd(&colsq[wc * 64 + col], q);
        }
    }
#pragma unroll
    for (int i = 0; i < 8; ++i) {
        int idx = i * 64 + ln;
        int row = idx >> 3, colq = (idx & 7) * 8;
        *(uint4*)(Y + (size_t)(mbase + wr * 64 + row) * NC + cbase + wc * 64 + colq) =
            *(const uint4*)&Cw[row * 64 + colq];
    }
    if (STATS) {
        __syncthreads();
        if (t < 128) {
            atomicAdd(&osum[blockIdx.x * 128 + t], colsum[t]);
            atomicAdd(&osq[blockIdx.x * 128 + t], colsq[t]);
        }
    }
}

// ---- sort machinery: histogram, 3-phase exclusive scan, index scatter ----
__global__ __launch_bounds__(256) void hist_kernel(const int* __restrict__ xy,
                                                   int* __restrict__ cnt)
{
    int p = blockIdx.x * 256 + threadIdx.x;
    if (p < NPTS) {
        int id = xy[(size_t)p * 2] * GYD + xy[(size_t)p * 2 + 1];
        atomicAdd(&cnt[id], 1);
    }
}

__global__ __launch_bounds__(256) void scanA_kernel(const int* __restrict__ cnt,
                                                    int* __restrict__ csum)
{
    __shared__ int red[256];
    int t = threadIdx.x, base = blockIdx.x * 2048;
    int s = 0;
    for (int i = t; i < 2048; i += 256) {
        int idx = base + i;
        if (idx < SEGR) s += cnt[idx];
    }
    red[t] = s; __syncthreads();
    for (int o = 128; o > 0; o >>= 1) { if (t < o) red[t] += red[t + o]; __syncthreads(); }
    if (t == 0) csum[blockIdx.x] = red[0];
}

__global__ void scanB_kernel(int* __restrict__ csum, int* __restrict__ offs)
{
    if (threadIdx.x == 0) {
        int run = 0;
        for (int i = 0; i < 64; ++i) { int v = csum[i]; csum[i] = run; run += v; }
        offs[SEGR] = run;
    }
}

__global__ __launch_bounds__(256) void scanC_kernel(const int* __restrict__ cnt,
                                                    const int* __restrict__ csum,
                                                    int* __restrict__ offs,
                                                    int* __restrict__ cursor)
{
    __shared__ int red[256];
    int t = threadIdx.x, base = blockIdx.x * 2048;
    int v[8]; int s = 0;
#pragma unroll
    for (int i = 0; i < 8; ++i) {
        int idx = base + t * 8 + i;
        v[i] = (idx < SEGR) ? cnt[idx] : 0;
        s += v[i];
    }
    red[t] = s; __syncthreads();
    for (int o = 1; o < 256; o <<= 1) {
        int x = (t >= o) ? red[t - o] : 0;
        __syncthreads();
        red[t] += x;
        __syncthreads();
    }
    int run = red[t] - s + csum[blockIdx.x];
#pragma unroll
    for (int i = 0; i < 8; ++i) {
        int idx = base + t * 8 + i;
        if (idx < SEGR) { offs[idx] = run; cursor[idx] = run; }
        run += v[i];
    }
}

__global__ __launch_bounds__(256) void scatter_idx_kernel(const int* __restrict__ xy,
                                                          int* __restrict__ cursor,
                                                          int* __restrict__ order)
{
    int p = blockIdx.x * 256 + threadIdx.x;
    if (p < NPTS) {
        int id = xy[(size_t)p * 2] * GYD + xy[(size_t)p * 2 + 1];
        int pos = atomicAdd(&cursor[id], 1);
        order[pos] = p;
    }
}

// ---- FUSED L4+segmax+W5+output v3: n-phase loop, A direct-to-register ----
// Per block (64 cells, contiguous sorted range): 8 n-phases of 64 L4 cols.
// Per phase: B-half (64x256, 32KB, XOR-swizzled both-sides) staged once;
// A-fragments load GLOBAL->VGPR per chunk (each lane owns one gathered row:
// 8 independent dwordx4 from a single 512B y3 row; L2-hot on phases 2..8);
// per-cell max lives in 16 regs/thread; per-phase seg (64x64) -> MFMA with
// the W5 k-slice accumulates E in registers. A never re-gathered per g (was
// 4x), no 64KB seg buffer, LDS 49KB -> 3 blocks/CU.
__global__ __launch_bounds__(256) void l4seg_kernel(
    const unsigned short* __restrict__ y3, const unsigned short* __restrict__ Wt4,
    const float* __restrict__ b4, const unsigned short* __restrict__ Wt5,
    const float* __restrict__ b5, const int* __restrict__ offs,
    const int* __restrict__ ord, float* __restrict__ out)
{
    __shared__ __align__(16) unsigned short Bsl[64 * 256];    // 32 KB
    __shared__ __align__(16) unsigned short w5s[32 * 64];     // 4 KB
    __shared__ __align__(16) unsigned short y4s[64 * 72];     // 9 KB (y4 chunk / seg)
    __shared__ float b4s[512];
    __shared__ int offs_s[65];
    __shared__ int osl[128];
    int t = threadIdx.x;
    int w = t >> 6, ln = t & 63, quad = ln >> 4, lr = ln & 15;
    int c0 = blockIdx.x * 64;
    if (t < 65) offs_s[t] = offs[c0 + t];
    for (int i = t; i < 512; i += 256) b4s[i] = b4[i];
    __syncthreads();
    const int jb = offs_s[0], je = offs_s[64];
    if (jb == je) {                               // whole block empty -> zeros
#pragma unroll
        for (int j = 0; j < 8; ++j)
            out[(size_t)(w * 8 + j) * NSEG + c0 + ln] = 0.f;
        return;
    }
    if (t < 128) { int aj = jb + t; osl[t] = (aj < je) ? ord[aj] : 0; }
    __syncthreads();

    const int cell = t >> 2, q = t & 3;
    const int cjb = offs_s[cell], cje = offs_s[cell + 1];

    f32x4 eacc[2];
    eacc[0] = (f32x4){0.f, 0.f, 0.f, 0.f};
    eacc[1] = (f32x4){0.f, 0.f, 0.f, 0.f};

    for (int p = 0; p < 8; ++p) {
        // ---- stage B half: 64 n-rows x 256 k, chunk_phys = chunk_log ^ (row&7)
#pragma unroll
        for (int i = 0; i < 8; ++i) {
            int rl = w * 16 + i * 2 + (ln >> 5);            // local B row 0..63
            int cl = (ln & 31) ^ (rl & 7);                  // source logical chunk
            async16(Wt4 + (size_t)(p * 64 + rl) * 256 + cl * 8,
                    Bsl + (w * 16 + i * 2) * 256 + ln * 8);
        }
        {   // w5 slice [32 heads][64 k], same swizzle
            int rl = t >> 3, cl = (t & 7) ^ (rl & 7);
            async16(Wt5 + (size_t)rl * 512 + p * 64 + cl * 8, w5s + t * 8);
        }
        float mxv[16];
#pragma unroll
        for (int i = 0; i < 16; ++i) mxv[i] = -3.0e38f;

        int chunk = 0;
        for (int cs = jb; cs < je; cs += 64, ++chunk) {
            int j = cs + w * 16 + lr; if (j >= je) j = je - 1;   // dup last (masked later)
            int idx = j - jb;
            int pr = (idx < 128) ? osl[idx] : ord[j];
            const unsigned short* Ar = y3 + (size_t)pr * 256 + quad * 8;
            short8 af[8];
#pragma unroll
            for (int r = 0; r < 8; ++r)
                af[r] = *(const short8*)(Ar + r * 32);
            f32x4 acc[4];
#pragma unroll
            for (int i = 0; i < 4; ++i) acc[i] = (f32x4){0.f, 0.f, 0.f, 0.f};
            if (chunk == 0) {                     // publish B (A regs auto-waited)
                asm volatile("s_waitcnt vmcnt(0)" ::: "memory");
                asm volatile("s_barrier" ::: "memory");
            }
#pragma unroll
            for (int r = 0; r < 8; ++r) {
                const int cp = (r * 4 + quad) ^ (lr & 7);   // phys chunk -> logical r*4+quad
#pragma unroll
                for (int ni = 0; ni < 4; ++ni) {
                    short8 bfr = *(const short8*)&Bsl[(ni * 16 + lr) * 256 + cp * 8];
                    acc[ni] = __builtin_amdgcn_mfma_f32_16x16x32_bf16(af[r], bfr, acc[ni], 0, 0, 0);
                }
            }
            // y4 (+b4) -> y4s  (row = chunk-local point, col = phase col)
#pragma unroll
            for (int ni = 0; ni < 4; ++ni) {
                float bv = b4s[p * 64 + ni * 16 + lr];
#pragma unroll
                for (int rr = 0; rr < 4; ++rr)
                    y4s[(w * 16 + quad * 4 + rr) * 72 + ni * 16 + lr] = f2bf(acc[ni][rr] + bv);
            }
            asm volatile("s_waitcnt lgkmcnt(0)" ::: "memory");
            asm volatile("s_barrier" ::: "memory");
            // per-cell running max (thread: cell x 16 cols of this phase)
            int lo = cjb > cs ? cjb : cs;
            int hi = cje < cs + 64 ? cje : cs + 64;
            for (int jj = lo; jj < hi; ++jj) {
                const uint4* rp = (const uint4*)&y4s[(jj - cs) * 72 + q * 16];
                uint4 v0 = rp[0], v1 = rp[1];
                unsigned int wv[8] = {v0.x, v0.y, v0.z, v0.w, v1.x, v1.y, v1.z, v1.w};
#pragma unroll
                for (int k2 = 0; k2 < 8; ++k2) {
                    mxv[2 * k2]     = fmaxf(mxv[2 * k2],     bf2f((unsigned short)(wv[k2] & 0xffffu)));
                    mxv[2 * k2 + 1] = fmaxf(mxv[2 * k2 + 1], bf2f((unsigned short)(wv[k2] >> 16)));
                }
            }
            asm volatile("s_barrier" ::: "memory");   // y4s free (next chunk / seg)
        }
        // seg -> y4s (empty cells -> 0, scatter semantics)
        {
            bool empty = (cjb == cje);
#pragma unroll
            for (int i = 0; i < 8; ++i) {
                float lo2 = empty ? 0.f : mxv[2 * i], hi2 = empty ? 0.f : mxv[2 * i + 1];
                *(unsigned int*)&y4s[cell * 72 + q * 16 + 2 * i] = pk_bf16(lo2, hi2);
            }
        }
        asm volatile("s_waitcnt lgkmcnt(0)" ::: "memory");
        asm volatile("s_barrier" ::: "memory");
        // E += seg @ W5 slice  (cells 64 x heads 32, k=64)
#pragma unroll
        for (int kt = 0; kt < 2; ++kt) {
            short8 af2 = *(const short8*)&y4s[(w * 16 + lr) * 72 + kt * 32 + quad * 8];
            const int cp = (kt * 4 + quad) ^ (lr & 7);
#pragma unroll
            for (int ni = 0; ni < 2; ++ni) {
                short8 bfr = *(const short8*)&w5s[(ni * 16 + lr) * 64 + cp * 8];
                eacc[ni] = __builtin_amdgcn_mfma_f32_16x16x32_bf16(af2, bfr, eacc[ni], 0, 0, 0);
            }
        }
        asm volatile("s_waitcnt lgkmcnt(0)" ::: "memory");
        asm volatile("s_barrier" ::: "memory");   // Bsl/w5s/y4s reusable next phase
    }
    // epilogue: relu(eacc+b5), occ mask, LDS stage (pad 33), coalesced write
    float* outs = (float*)&Bsl[0];                // 64*33*4 = 8448 B, reuses Bsl
#pragma unroll
    for (int ni = 0; ni < 2; ++ni) {
        int h = ni * 16 + lr;
        float bv = b5[h];
#pragma unroll
        for (int rr = 0; rr < 4; ++rr) {
            int cr = w * 16 + quad * 4 + rr;
            bool oc = offs_s[cr + 1] > offs_s[cr];
            outs[cr * 33 + h] = oc ? fmaxf(eacc[ni][rr] + bv, 0.f) : 0.f;
        }
    }
    __syncthreads();
#pragma unroll
    for (int j = 0; j < 8; ++j)
        out[(size_t)(w * 8 + j) * NSEG + c0 + ln] = outs[ln * 33 + w * 8 + j];
}

// ---- zero the gx>=360 tail of out (cells SEGR..NSEG never occur) ----
__global__ __launch_bounds__(256) void ztail_kernel(float* __restrict__ out)
{
    int i = blockIdx.x * 256 + threadIdx.x;       // grid exact: 1350*256 = 345600
    const int per = (NSEG - SEGR) / 4;            // 10800 float4 per h
    int h = i / per, c = i % per;
    *(float4*)(out + (size_t)h * NSEG + SEGR + (size_t)c * 4) = make_float4(0.f, 0.f, 0.f, 0.f);
}

extern "C" void kernel_launch(void* const* d_in, const int* in_sizes, int n_in,
                              void* d_out, int out_size, void* d_ws, size_t ws_size,
                              hipStream_t stream)
{
    const float* pt_fea = (const float*)d_in[0];
    const int*   xy_ind = (const int*)d_in[1];
    const float* bn0_g  = (const float*)d_in[2];
    const float* bn0_b  = (const float*)d_in[3];
    const float* W1     = (const float*)d_in[4];
    const float* b1     = (const float*)d_in[5];
    const float* bn1_g  = (const float*)d_in[6];
    const float* bn1_b  = (const float*)d_in[7];
    const float* W2     = (const float*)d_in[8];
    const float* b2     = (const float*)d_in[9];
    const float* bn2_g  = (const float*)d_in[10];
    const float* bn2_b  = (const float*)d_in[11];
    const float* W3     = (const float*)d_in[12];
    const float* b3     = (const float*)d_in[13];
    const float* bn3_g  = (const float*)d_in[14];
    const float* bn3_b  = (const float*)d_in[15];
    const float* W4     = (const float*)d_in[16];
    const float* b4     = (const float*)d_in[17];
    const float* W5     = (const float*)d_in[18];
    const float* b5     = (const float*)d_in[19];
    float* out = (float*)d_out;

    // ---- workspace layout (unchanged offsets; E/y4g regions now unused) ----
    const size_t oY2   = 61472768;                 // MPAD*256*2
    const size_t oE    = oY2 + (size_t)MPAD * 128 * 2;
    const size_t oCnt  = oE + (size_t)SEGR * 32 * 4;
    const size_t oOffs = oCnt + 518400;
    const size_t oCur  = oOffs + 518528;
    const size_t oOrd  = oCur + 518400;
    const size_t oCsum = oOrd + 480000;
    const size_t oSt   = oCsum + 512;
    const size_t oWt2  = oSt + 16384;
    const size_t oWt3  = oWt2 + 16384;
    const size_t oWt4  = oWt3 + 65536;
    const size_t oWt5  = oWt4 + 262144;

    unsigned short* y1   = (unsigned short*)d_ws;
    unsigned short* y3   = (unsigned short*)d_ws;
    unsigned short* y2   = (unsigned short*)((char*)d_ws + oY2);
    int*            cnt  = (int*)((char*)d_ws + oCnt);
    int*            offs = (int*)((char*)d_ws + oOffs);
    int*            cur  = (int*)((char*)d_ws + oCur);
    int*            ord  = (int*)((char*)d_ws + oOrd);
    int*            csum = (int*)((char*)d_ws + oCsum);
    float*          st   = (float*)((char*)d_ws + oSt);
    unsigned short* Wt2  = (unsigned short*)((char*)d_ws + oWt2);
    unsigned short* Wt3  = (unsigned short*)((char*)d_ws + oWt3);
    unsigned short* Wt4  = (unsigned short*)((char*)d_ws + oWt4);
    unsigned short* Wt5  = (unsigned short*)((char*)d_ws + oWt5);

    float* s0 = st + 0;     float* q0 = st + 8;
    float* W1p = st + 16;   float* b1p = st + 464;
    float* sum1 = st + 528; float* sq1 = st + 592; float* sc1 = st + 656; float* sh1 = st + 720;
    float* sum2 = st + 784; float* sq2 = st + 912; float* sc2 = st + 1040; float* sh2 = st + 1168;
    float* sum3 = st + 1296; float* sq3 = st + 1552; float* sc3 = st + 1808; float* sh3 = st + 2064;

    wtrans_kernel<<<(64 * 128 + 255) / 256, 256, 0, stream>>>(W2, Wt2, 64, 128);
    wtrans_kernel<<<(128 * 256 + 255) / 256, 256, 0, stream>>>(W3, Wt3, 128, 256);
    wtrans_kernel<<<(256 * 512 + 255) / 256, 256, 0, stream>>>(W4, Wt4, 256, 512);
    wtrans_kernel<<<(512 * 32 + 255) / 256, 256, 0, stream>>>(W5, Wt5, 512, 32);

    for (int b = 0; b < 2; ++b) {
        const float* fea_b = pt_fea + (size_t)b * NPTS * 7;
        const int*   xy_b  = xy_ind + (size_t)b * NPTS * 2;
        float*       out_b = out + (size_t)b * NHD * NSEG;

        (void)hipMemsetAsync(st, 0, 2320 * sizeof(float), stream);
        (void)hipMemsetAsync(cnt, 0, (size_t)SEGR * 4, stream);

        bn0_stats_kernel<<<128, 256, 0, stream>>>(fea_b, s0, q0);
        prep0_kernel<<<1, 64, 0, stream>>>(s0, q0, bn0_g, bn0_b, W1, b1, W1p, b1p);
        layer1_kernel<<<MPAD / 256, 256, 0, stream>>>(fea_b, W1p, b1p, y1, sum1, sq1);
        prep_bn_kernel<<<1, 64, 0, stream>>>(sum1, sq1, bn1_g, bn1_b, sc1, sh1, 64);
        bnrelu_kernel<64><<<1024, 256, 0, stream>>>(y1, sc1, sh1);
        gemm_quad<64, 128, true><<<dim3(1, MB128), 256, 0, stream>>>(
            y1, Wt2, b2, y2, sum2, sq2);
        prep_bn_kernel<<<1, 128, 0, stream>>>(sum2, sq2, bn2_g, bn2_b, sc2, sh2, 128);
        bnrelu_kernel<128><<<2048, 256, 0, stream>>>(y2, sc2, sh2);
        gemm_quad<128, 256, true><<<dim3(2, MB128), 256, 0, stream>>>(
            y2, Wt3, b3, y3, sum3, sq3);
        prep_bn_kernel<<<1, 256, 0, stream>>>(sum3, sq3, bn3_g, bn3_b, sc3, sh3, 256);
        bnrelu_kernel<256><<<2048, 256, 0, stream>>>(y3, sc3, sh3);

        hist_kernel<<<(NPTS + 255) / 256, 256, 0, stream>>>(xy_b, cnt);
        scanA_kernel<<<64, 256, 0, stream>>>(cnt, csum);
        scanB_kernel<<<1, 64, 0, stream>>>(csum, offs);
        scanC_kernel<<<64, 256, 0, stream>>>(cnt, csum, offs, cur);
        scatter_idx_kernel<<<(NPTS + 255) / 256, 256, 0, stream>>>(xy_b, cur, ord);

        l4seg_kernel<<<SEGR / 64, 256, 0, stream>>>(y3, Wt4, b4, Wt5, b5, offs, ord, out_b);
        ztail_kernel<<<1350, 256, 0, stream>>>(out_b);
    }
}